// Round 1
// baseline (1236.985 us; speedup 1.0000x reference)
//
#include <hip/hip_runtime.h>
#include <hip/hip_bf16.h>

#define CS 768
#define NTOK 1024
#define CZ 128
#define NH 12
#define HD 64

#define GM_NONE 0
#define GM_BIAS 1
#define GM_SIG  2
#define GM_GMUL 3

// ---------------- LayerNorm over s: (1024, 768) ----------------
__global__ __launch_bounds__(256) void ln_s_kernel(const float* __restrict__ s,
    const float* __restrict__ sc, const float* __restrict__ bi, float* __restrict__ sn) {
  int row = blockIdx.x;
  const float* x = s + (size_t)row * CS;
  int tid = threadIdx.x;
  float v0 = x[tid], v1 = x[tid + 256], v2 = x[tid + 512];
  float sum = v0 + v1 + v2;
  float sq  = v0*v0 + v1*v1 + v2*v2;
  for (int off = 1; off < 64; off <<= 1) {
    sum += __shfl_xor(sum, off);
    sq  += __shfl_xor(sq,  off);
  }
  __shared__ float ws1[4], ws2[4];
  if ((tid & 63) == 0) { ws1[tid >> 6] = sum; ws2[tid >> 6] = sq; }
  __syncthreads();
  float S = ws1[0] + ws1[1] + ws1[2] + ws1[3];
  float Q = ws2[0] + ws2[1] + ws2[2] + ws2[3];
  float mu  = S * (1.f / CS);
  float var = Q * (1.f / CS) - mu * mu;
  float rs  = rsqrtf(var + 1e-5f);
  float* y = sn + (size_t)row * CS;
  y[tid]       = (v0 - mu) * rs * sc[tid]       + bi[tid];
  y[tid + 256] = (v1 - mu) * rs * sc[tid + 256] + bi[tid + 256];
  y[tid + 512] = (v2 - mu) * rs * sc[tid + 512] + bi[tid + 512];
}

// ---------------- zb: LN(z) @ Wz -> (12, 1024, 1024) ----------------
// 16 lanes per (i,j) pair, 4 pairs per wave. Wz/scale/bias rows held in registers.
__global__ __launch_bounds__(256) void zb_kernel(const float* __restrict__ z,
    const float* __restrict__ gs, const float* __restrict__ gb,
    const float* __restrict__ Wz, float* __restrict__ zb) {
  const int lane = threadIdx.x & 63;
  const int sub  = lane & 15;   // c-group within pair
  const int slot = lane >> 4;   // pair slot within wave
  const int waveId = blockIdx.x * (blockDim.x >> 6) + (threadIdx.x >> 6);
  const int nWaves = gridDim.x * (blockDim.x >> 6);
  const int cA = sub * 4, cB = 64 + sub * 4;

  float wza[4][12], wzb[4][12];
  float sa[4], sb[4], ba[4], bb[4];
  #pragma unroll
  for (int u = 0; u < 4; ++u) {
    sa[u] = gs[cA + u]; ba[u] = gb[cA + u];
    sb[u] = gs[cB + u]; bb[u] = gb[cB + u];
    #pragma unroll
    for (int h = 0; h < NH; ++h) {
      wza[u][h] = Wz[(cA + u) * NH + h];
      wzb[u][h] = Wz[(cB + u) * NH + h];
    }
  }

  const int NPAIR = NTOK * NTOK;
  const int NQUAD = NPAIR / 4;
  for (int quad = waveId; quad < NQUAD; quad += nWaves) {
    int p = quad * 4 + slot;
    const float* zp = z + (size_t)p * CZ;
    float4 za = *(const float4*)(zp + cA);
    float4 zc = *(const float4*)(zp + cB);
    float zav[4] = {za.x, za.y, za.z, za.w};
    float zbv[4] = {zc.x, zc.y, zc.z, zc.w};

    float sum = 0.f, sq = 0.f;
    #pragma unroll
    for (int u = 0; u < 4; ++u) {
      sum += zav[u] + zbv[u];
      sq = fmaf(zav[u], zav[u], sq);
      sq = fmaf(zbv[u], zbv[u], sq);
    }
    #pragma unroll
    for (int m = 1; m < 16; m <<= 1) {
      sum += __shfl_xor(sum, m);
      sq  += __shfl_xor(sq,  m);
    }
    float mu  = sum * (1.f / CZ);
    float var = sq * (1.f / CZ) - mu * mu;
    float rs  = rsqrtf(var + 1e-5f);

    float acc[NH] = {};
    #pragma unroll
    for (int u = 0; u < 4; ++u) {
      float nva = fmaf((zav[u] - mu) * rs, sa[u], ba[u]);
      float nvb = fmaf((zbv[u] - mu) * rs, sb[u], bb[u]);
      #pragma unroll
      for (int h = 0; h < NH; ++h) {
        acc[h] = fmaf(nva, wza[u][h], acc[h]);
        acc[h] = fmaf(nvb, wzb[u][h], acc[h]);
      }
    }
    #pragma unroll
    for (int h = 0; h < NH; ++h) {
      float t = acc[h];
      #pragma unroll
      for (int m = 1; m < 16; m <<= 1) t += __shfl_xor(t, m);
      if (sub == 0) zb[(size_t)h * NPAIR + p] = t;
    }
  }
}

// ---------------- generic fp32 GEMM: C = f(A[*A2] @ W [+ bias]) ----------------
__global__ __launch_bounds__(256) void gemm_f32(const float* __restrict__ A,
    const float* __restrict__ A2, const float* __restrict__ W,
    const float* __restrict__ bias, float* __restrict__ C,
    int M, int K, int N, int mode) {
  __shared__ float As[16][65];
  __shared__ float Bs[16][65];
  int tx = threadIdx.x, ty = threadIdx.y;
  int tid = ty * 16 + tx;
  int row0 = blockIdx.y * 64, col0 = blockIdx.x * 64;
  float acc[4][4] = {};
  for (int k0 = 0; k0 < K; k0 += 16) {
    for (int idx = tid; idx < 1024; idx += 256) {
      int m = idx >> 4, kk = idx & 15;
      float a = A[(size_t)(row0 + m) * K + k0 + kk];
      if (mode == GM_GMUL) a *= A2[(size_t)(row0 + m) * K + k0 + kk];
      As[kk][m] = a;
    }
    for (int idx = tid; idx < 1024; idx += 256) {
      int kk = idx >> 6, n = idx & 63;
      Bs[kk][n] = W[(size_t)(k0 + kk) * N + col0 + n];
    }
    __syncthreads();
    #pragma unroll
    for (int kk = 0; kk < 16; ++kk) {
      float a[4], b[4];
      #pragma unroll
      for (int u = 0; u < 4; ++u) { a[u] = As[kk][ty*4+u]; b[u] = Bs[kk][tx*4+u]; }
      #pragma unroll
      for (int i = 0; i < 4; ++i)
        #pragma unroll
        for (int j = 0; j < 4; ++j) acc[i][j] = fmaf(a[i], b[j], acc[i][j]);
    }
    __syncthreads();
  }
  for (int i = 0; i < 4; ++i) {
    int m = row0 + ty * 4 + i;
    int n = col0 + tx * 4;
    float4 r = make_float4(acc[i][0], acc[i][1], acc[i][2], acc[i][3]);
    if (mode == GM_BIAS) { r.x += bias[n]; r.y += bias[n+1]; r.z += bias[n+2]; r.w += bias[n+3]; }
    if (mode == GM_SIG) {
      r.x = 1.f / (1.f + __expf(-r.x));
      r.y = 1.f / (1.f + __expf(-r.y));
      r.z = 1.f / (1.f + __expf(-r.z));
      r.w = 1.f / (1.f + __expf(-r.w));
    }
    *(float4*)(C + (size_t)m * N + n) = r;
  }
}

// ---------------- scores: attn[h,i,j] = qk/8 + zb + maskterm ----------------
__global__ __launch_bounds__(256) void scores_kernel(const float* __restrict__ q,
    const float* __restrict__ k, const float* __restrict__ mask, float* __restrict__ attn) {
  int h = blockIdx.z;
  int i0 = blockIdx.y * 64, j0 = blockIdx.x * 64;
  __shared__ float Qs[64][65], Ks[64][65];
  int tx = threadIdx.x, ty = threadIdx.y;
  int tid = ty * 16 + tx;
  for (int idx = tid; idx < 4096; idx += 256) {
    int r = idx >> 6, d = idx & 63;
    Qs[r][d] = q[(size_t)(i0 + r) * CS + h * HD + d];
    Ks[r][d] = k[(size_t)(j0 + r) * CS + h * HD + d];
  }
  __syncthreads();
  float acc[4][4] = {};
  #pragma unroll 16
  for (int d = 0; d < 64; ++d) {
    float a[4], b[4];
    #pragma unroll
    for (int u = 0; u < 4; ++u) { a[u] = Qs[ty*4+u][d]; b[u] = Ks[tx*4+u][d]; }
    #pragma unroll
    for (int i = 0; i < 4; ++i)
      #pragma unroll
      for (int j = 0; j < 4; ++j) acc[i][j] = fmaf(a[i], b[j], acc[i][j]);
  }
  int gj = j0 + tx * 4;
  float4 mk = *(const float4*)(mask + gj);
  float4 mt;
  mt.x = (1.f - mk.x) * -1000000.0f;
  mt.y = (1.f - mk.y) * -1000000.0f;
  mt.z = (1.f - mk.z) * -1000000.0f;
  mt.w = (1.f - mk.w) * -1000000.0f;
  for (int i = 0; i < 4; ++i) {
    int gi = i0 + ty * 4 + i;
    size_t off = ((size_t)h << 20) + ((size_t)gi << 10) + gj;
    float4 zb4 = *(const float4*)(attn + off);
    float4 r;
    r.x = fmaf(acc[i][0], 0.125f, zb4.x) + mt.x;
    r.y = fmaf(acc[i][1], 0.125f, zb4.y) + mt.y;
    r.z = fmaf(acc[i][2], 0.125f, zb4.z) + mt.z;
    r.w = fmaf(acc[i][3], 0.125f, zb4.w) + mt.w;
    *(float4*)(attn + off) = r;
  }
}

// ---------------- softmax over last dim of (12*1024, 1024) ----------------
__global__ __launch_bounds__(256) void softmax_kernel(float* __restrict__ attn) {
  size_t row = blockIdx.x;
  float* p = attn + (row << 10);
  int tid = threadIdx.x;
  float4 v = *(float4*)(p + tid * 4);
  float m = fmaxf(fmaxf(v.x, v.y), fmaxf(v.z, v.w));
  for (int off = 1; off < 64; off <<= 1) m = fmaxf(m, __shfl_xor(m, off));
  __shared__ float wm[4], wsum[4];
  if ((tid & 63) == 0) wm[tid >> 6] = m;
  __syncthreads();
  m = fmaxf(fmaxf(wm[0], wm[1]), fmaxf(wm[2], wm[3]));
  v.x = __expf(v.x - m); v.y = __expf(v.y - m);
  v.z = __expf(v.z - m); v.w = __expf(v.w - m);
  float sm = v.x + v.y + v.z + v.w;
  for (int off = 1; off < 64; off <<= 1) sm += __shfl_xor(sm, off);
  if ((tid & 63) == 0) wsum[tid >> 6] = sm;
  __syncthreads();
  sm = wsum[0] + wsum[1] + wsum[2] + wsum[3];
  float inv = 1.f / sm;
  v.x *= inv; v.y *= inv; v.z *= inv; v.w *= inv;
  *(float4*)(p + tid * 4) = v;
}

// ---------------- PV: o[i, h*64+d] = sum_j attn[h,i,j] v[j, h*64+d] ----------------
__global__ __launch_bounds__(256) void pv_kernel(const float* __restrict__ attn,
    const float* __restrict__ v, float* __restrict__ o) {
  int h = blockIdx.y;
  int i0 = blockIdx.x * 64;
  int tx = threadIdx.x, ty = threadIdx.y;
  int tid = ty * 16 + tx;
  __shared__ float As[16][65], Bs[16][65];
  float acc[4][4] = {};
  for (int j0 = 0; j0 < NTOK; j0 += 16) {
    for (int idx = tid; idx < 1024; idx += 256) {
      int r = idx >> 4, c = idx & 15;
      As[c][r] = attn[((size_t)h << 20) + ((size_t)(i0 + r) << 10) + j0 + c];
    }
    for (int idx = tid; idx < 1024; idx += 256) {
      int r = idx >> 6, c = idx & 63;
      Bs[r][c] = v[(size_t)(j0 + r) * CS + h * HD + c];
    }
    __syncthreads();
    #pragma unroll
    for (int kk = 0; kk < 16; ++kk) {
      float a[4], b[4];
      #pragma unroll
      for (int u = 0; u < 4; ++u) { a[u] = As[kk][ty*4+u]; b[u] = Bs[kk][tx*4+u]; }
      #pragma unroll
      for (int i = 0; i < 4; ++i)
        #pragma unroll
        for (int j = 0; j < 4; ++j) acc[i][j] = fmaf(a[i], b[j], acc[i][j]);
    }
    __syncthreads();
  }
  for (int i = 0; i < 4; ++i) {
    size_t off = (size_t)(i0 + ty * 4 + i) * CS + h * HD + tx * 4;
    *(float4*)(o + off) = make_float4(acc[i][0], acc[i][1], acc[i][2], acc[i][3]);
  }
}

extern "C" void kernel_launch(void* const* d_in, const int* in_sizes, int n_in,
                              void* d_out, int out_size, void* d_ws, size_t ws_size,
                              hipStream_t stream) {
  const float* s    = (const float*)d_in[0];
  const float* z    = (const float*)d_in[1];
  const float* mask = (const float*)d_in[2];
  const float* nss  = (const float*)d_in[3];
  const float* nsb  = (const float*)d_in[4];
  const float* Wq   = (const float*)d_in[5];
  const float* bq   = (const float*)d_in[6];
  const float* Wk   = (const float*)d_in[7];
  const float* Wv   = (const float*)d_in[8];
  const float* Wg   = (const float*)d_in[9];
  const float* nzs  = (const float*)d_in[10];
  const float* nzb  = (const float*)d_in[11];
  const float* Wz   = (const float*)d_in[12];
  const float* Wo   = (const float*)d_in[13];
  float* out = (float*)d_out;
  float* ws = (float*)d_ws;

  const size_t SN = (size_t)NTOK * CS;         // 786432
  float* sn   = ws;
  float* q    = sn + SN;
  float* k    = q  + SN;
  float* v    = k  + SN;
  float* g    = v  + SN;
  float* o    = g  + SN;
  float* attn = o  + SN;                       // 12 * 1024 * 1024

  dim3 t16(16, 16);
  ln_s_kernel<<<NTOK, 256, 0, stream>>>(s, nss, nsb, sn);
  zb_kernel<<<2048, 256, 0, stream>>>(z, nzs, nzb, Wz, attn);
  gemm_f32<<<dim3(12, 16), t16, 0, stream>>>(sn, nullptr, Wq, bq,      q,   NTOK, CS, CS, GM_BIAS);
  gemm_f32<<<dim3(12, 16), t16, 0, stream>>>(sn, nullptr, Wk, nullptr, k,   NTOK, CS, CS, GM_NONE);
  gemm_f32<<<dim3(12, 16), t16, 0, stream>>>(sn, nullptr, Wv, nullptr, v,   NTOK, CS, CS, GM_NONE);
  gemm_f32<<<dim3(12, 16), t16, 0, stream>>>(sn, nullptr, Wg, nullptr, g,   NTOK, CS, CS, GM_SIG);
  scores_kernel<<<dim3(16, 16, 12), t16, 0, stream>>>(q, k, mask, attn);
  softmax_kernel<<<NH * NTOK, 256, 0, stream>>>(attn);
  pv_kernel<<<dim3(16, 12), t16, 0, stream>>>(attn, v, o);
  gemm_f32<<<dim3(12, 16), t16, 0, stream>>>(o, g, Wo, nullptr, out, NTOK, CS, CS, GM_GMUL);
}

// Round 2
// 423.600 us; speedup vs baseline: 2.9202x; 2.9202x over previous
//
#include <hip/hip_runtime.h>
#include <hip/hip_bf16.h>

#define CS 768
#define NTOK 1024
#define CZ 128
#define NH 12
#define HD 64

#define GB_BF16  0
#define GB_BIAS  1
#define GB_SIG   2
#define GB_TRANS 3
#define GB_F32   4

typedef __attribute__((ext_vector_type(8))) short bf16x8;
typedef __attribute__((ext_vector_type(4))) float f32x4;
typedef __attribute__((ext_vector_type(8))) unsigned short ushort8_t;
typedef __attribute__((ext_vector_type(4))) unsigned short ushort4_t;

__device__ inline unsigned short f2bf(float f) {
  __hip_bfloat16 h = __float2bfloat16(f);
  return *reinterpret_cast<unsigned short*>(&h);
}
__device__ inline float bf2f(unsigned short u) {
  unsigned int t = ((unsigned int)u) << 16;
  union { unsigned int i; float f; } c; c.i = t;
  return c.f;
}

// ---------------- LayerNorm over s: (1024, 768) -> bf16 ----------------
__global__ __launch_bounds__(256) void ln_s_kernel(const float* __restrict__ s,
    const float* __restrict__ sc, const float* __restrict__ bi, unsigned short* __restrict__ sn) {
  int row = blockIdx.x;
  const float* x = s + (size_t)row * CS;
  int tid = threadIdx.x;
  float v0 = x[tid], v1 = x[tid + 256], v2 = x[tid + 512];
  float sum = v0 + v1 + v2;
  float sq  = v0*v0 + v1*v1 + v2*v2;
  for (int off = 1; off < 64; off <<= 1) {
    sum += __shfl_xor(sum, off);
    sq  += __shfl_xor(sq,  off);
  }
  __shared__ float ws1[4], ws2[4];
  if ((tid & 63) == 0) { ws1[tid >> 6] = sum; ws2[tid >> 6] = sq; }
  __syncthreads();
  float S = ws1[0] + ws1[1] + ws1[2] + ws1[3];
  float Q = ws2[0] + ws2[1] + ws2[2] + ws2[3];
  float mu  = S * (1.f / CS);
  float var = Q * (1.f / CS) - mu * mu;
  float rs  = rsqrtf(var + 1e-5f);
  unsigned short* y = sn + (size_t)row * CS;
  y[tid]       = f2bf((v0 - mu) * rs * sc[tid]       + bi[tid]);
  y[tid + 256] = f2bf((v1 - mu) * rs * sc[tid + 256] + bi[tid + 256]);
  y[tid + 512] = f2bf((v2 - mu) * rs * sc[tid + 512] + bi[tid + 512]);
}

// ---------------- transpose+convert 5 weights (768x768 f32) -> bf16 N x K ----------------
__global__ __launch_bounds__(256) void cvt_w_kernel(const float* __restrict__ W0,
    const float* __restrict__ W1, const float* __restrict__ W2,
    const float* __restrict__ W3, const float* __restrict__ W4,
    unsigned short* __restrict__ out) {
  const float* W = blockIdx.z == 0 ? W0 : blockIdx.z == 1 ? W1 :
                   blockIdx.z == 2 ? W2 : blockIdx.z == 3 ? W3 : W4;
  unsigned short* Wt = out + (size_t)blockIdx.z * CS * CS;
  __shared__ float tile[64][65];
  int k0 = blockIdx.x * 64, n0 = blockIdx.y * 64;
  int t = threadIdx.x;
  #pragma unroll
  for (int it = 0; it < 4; ++it) {
    int r = (t >> 4) + it * 16;
    int c = (t & 15) * 4;
    float4 vv = *(const float4*)(W + (size_t)(k0 + r) * CS + n0 + c);
    tile[r][c] = vv.x; tile[r][c+1] = vv.y; tile[r][c+2] = vv.z; tile[r][c+3] = vv.w;
  }
  __syncthreads();
  #pragma unroll
  for (int it = 0; it < 2; ++it) {
    int idx = t + it * 256;
    int n = idx >> 3, k8 = (idx & 7) * 8;
    ushort8_t o;
    #pragma unroll
    for (int e = 0; e < 8; ++e) o[e] = f2bf(tile[k8 + e][n]);
    *(ushort8_t*)(Wt + (size_t)(n0 + n) * CS + k0 + k8) = o;
  }
}

// ---------------- zb: LN(z) @ Wz -> (12, 1024, 1024) fp32 ----------------
__global__ __launch_bounds__(256) void zb_kernel(const float* __restrict__ z,
    const float* __restrict__ gs, const float* __restrict__ gb,
    const float* __restrict__ Wz, float* __restrict__ zb) {
  const int lane = threadIdx.x & 63;
  const int sub  = lane & 15;
  const int slot = lane >> 4;
  const int waveId = blockIdx.x * (blockDim.x >> 6) + (threadIdx.x >> 6);
  const int nWaves = gridDim.x * (blockDim.x >> 6);
  const int cA = sub * 4, cB = 64 + sub * 4;

  float wza[4][12], wzb[4][12];
  float sa[4], sb[4], ba[4], bb[4];
  #pragma unroll
  for (int u = 0; u < 4; ++u) {
    sa[u] = gs[cA + u]; ba[u] = gb[cA + u];
    sb[u] = gs[cB + u]; bb[u] = gb[cB + u];
    #pragma unroll
    for (int h = 0; h < NH; ++h) {
      wza[u][h] = Wz[(cA + u) * NH + h];
      wzb[u][h] = Wz[(cB + u) * NH + h];
    }
  }

  const int NPAIR = NTOK * NTOK;
  const int NQUAD = NPAIR / 4;
  for (int quad = waveId; quad < NQUAD; quad += nWaves) {
    int p = quad * 4 + slot;
    const float* zp = z + (size_t)p * CZ;
    float4 za = *(const float4*)(zp + cA);
    float4 zc = *(const float4*)(zp + cB);
    float zav[4] = {za.x, za.y, za.z, za.w};
    float zbv[4] = {zc.x, zc.y, zc.z, zc.w};

    float sum = 0.f, sq = 0.f;
    #pragma unroll
    for (int u = 0; u < 4; ++u) {
      sum += zav[u] + zbv[u];
      sq = fmaf(zav[u], zav[u], sq);
      sq = fmaf(zbv[u], zbv[u], sq);
    }
    #pragma unroll
    for (int m = 1; m < 16; m <<= 1) {
      sum += __shfl_xor(sum, m);
      sq  += __shfl_xor(sq,  m);
    }
    float mu  = sum * (1.f / CZ);
    float var = sq * (1.f / CZ) - mu * mu;
    float rs  = rsqrtf(var + 1e-5f);

    float acc[NH] = {};
    #pragma unroll
    for (int u = 0; u < 4; ++u) {
      float nva = fmaf((zav[u] - mu) * rs, sa[u], ba[u]);
      float nvb = fmaf((zbv[u] - mu) * rs, sb[u], bb[u]);
      #pragma unroll
      for (int h = 0; h < NH; ++h) {
        acc[h] = fmaf(nva, wza[u][h], acc[h]);
        acc[h] = fmaf(nvb, wzb[u][h], acc[h]);
      }
    }
    #pragma unroll
    for (int h = 0; h < NH; ++h) {
      float t = acc[h];
      #pragma unroll
      for (int m = 1; m < 16; m <<= 1) t += __shfl_xor(t, m);
      if (sub == 0) zb[(size_t)h * NPAIR + p] = t;
    }
  }
}

// ---------------- bf16 MFMA GEMM: C = f(A @ Bt^T) ----------------
// A: M x K bf16 row-major. Bt: N x K bf16 (pre-transposed weights).
__global__ __launch_bounds__(256) void gemm_bf16(const unsigned short* __restrict__ A,
    const unsigned short* __restrict__ Bt, const float* __restrict__ bias,
    void* __restrict__ Cout, int M, int K, int N, int mode) {
  __shared__ __align__(16) unsigned short As[64][40];
  __shared__ __align__(16) unsigned short Bs[64][40];
  int tid = threadIdx.x;
  int wid = tid >> 6, lane = tid & 63;
  int lrow = lane & 15, lk8 = (lane >> 4) * 8;
  int row0 = blockIdx.y * 64, col0 = blockIdx.x * 64;
  int ar = tid >> 2, ak = (tid & 3) * 8;
  f32x4 acc[4] = {};
  for (int k0 = 0; k0 < K; k0 += 32) {
    *(ushort8_t*)&As[ar][ak] = *(const ushort8_t*)(A  + (size_t)(row0 + ar) * K + k0 + ak);
    *(ushort8_t*)&Bs[ar][ak] = *(const ushort8_t*)(Bt + (size_t)(col0 + ar) * K + k0 + ak);
    __syncthreads();
    bf16x8 af = *(bf16x8*)&As[wid * 16 + lrow][lk8];
    #pragma unroll
    for (int nb = 0; nb < 4; ++nb) {
      bf16x8 bfr = *(bf16x8*)&Bs[nb * 16 + lrow][lk8];
      acc[nb] = __builtin_amdgcn_mfma_f32_16x16x32_bf16(af, bfr, acc[nb], 0, 0, 0);
    }
    __syncthreads();
  }
  #pragma unroll
  for (int nb = 0; nb < 4; ++nb) {
    #pragma unroll
    for (int r = 0; r < 4; ++r) {
      int grow = row0 + wid * 16 + (lane >> 4) * 4 + r;
      int gcol = col0 + nb * 16 + lrow;
      float v = acc[nb][r];
      if (mode == GB_BIAS) v += bias[gcol];
      if (mode == GB_SIG)  v = 1.f / (1.f + __expf(-v));
      if (mode == GB_F32)
        ((float*)Cout)[(size_t)grow * N + gcol] = v;
      else if (mode == GB_TRANS)
        ((unsigned short*)Cout)[(size_t)gcol * M + grow] = f2bf(v);
      else
        ((unsigned short*)Cout)[(size_t)grow * N + gcol] = f2bf(v);
    }
  }
}

// ---------------- scores: sbuf[h,i,j] = qk/8 + zb + maskterm (MFMA) ----------------
__global__ __launch_bounds__(256) void scores_mfma(const unsigned short* __restrict__ q,
    const unsigned short* __restrict__ k, const float* __restrict__ zbuf,
    const float* __restrict__ mask, float* __restrict__ sbuf) {
  int h = blockIdx.z, i0 = blockIdx.y * 64, j0 = blockIdx.x * 64;
  __shared__ __align__(16) unsigned short Qs[64][72], Ks[64][72];
  int tid = threadIdx.x, wid = tid >> 6, lane = tid & 63;
  int lrow = lane & 15, lk8 = (lane >> 4) * 8;
  #pragma unroll
  for (int it = 0; it < 2; ++it) {
    int idx = tid + it * 256;
    int r = idx >> 3, d8 = (idx & 7) * 8;
    *(ushort8_t*)&Qs[r][d8] = *(const ushort8_t*)(q + (size_t)(i0 + r) * CS + h * HD + d8);
    *(ushort8_t*)&Ks[r][d8] = *(const ushort8_t*)(k + (size_t)(j0 + r) * CS + h * HD + d8);
  }
  __syncthreads();
  f32x4 acc[4] = {};
  #pragma unroll
  for (int ks = 0; ks < 2; ++ks) {
    bf16x8 af = *(bf16x8*)&Qs[wid * 16 + lrow][ks * 32 + lk8];
    #pragma unroll
    for (int nb = 0; nb < 4; ++nb) {
      bf16x8 bfr = *(bf16x8*)&Ks[nb * 16 + lrow][ks * 32 + lk8];
      acc[nb] = __builtin_amdgcn_mfma_f32_16x16x32_bf16(af, bfr, acc[nb], 0, 0, 0);
    }
  }
  #pragma unroll
  for (int nb = 0; nb < 4; ++nb) {
    int gj = j0 + nb * 16 + lrow;
    float mt = (1.f - mask[gj]) * -1000000.0f;
    #pragma unroll
    for (int r = 0; r < 4; ++r) {
      int gi = i0 + wid * 16 + (lane >> 4) * 4 + r;
      size_t off = ((size_t)h << 20) + ((size_t)gi << 10) + gj;
      sbuf[off] = fmaf(acc[nb][r], 0.125f, zbuf[off]) + mt;
    }
  }
}

// ---------------- softmax: fp32 scores -> bf16 probs ----------------
__global__ __launch_bounds__(256) void softmax_kernel(const float* __restrict__ sbuf,
    unsigned short* __restrict__ probs) {
  size_t row = blockIdx.x;
  const float* p = sbuf + (row << 10);
  int tid = threadIdx.x;
  float4 v = *(const float4*)(p + tid * 4);
  float m = fmaxf(fmaxf(v.x, v.y), fmaxf(v.z, v.w));
  for (int off = 1; off < 64; off <<= 1) m = fmaxf(m, __shfl_xor(m, off));
  __shared__ float wm[4], wsum[4];
  if ((tid & 63) == 0) wm[tid >> 6] = m;
  __syncthreads();
  m = fmaxf(fmaxf(wm[0], wm[1]), fmaxf(wm[2], wm[3]));
  v.x = __expf(v.x - m); v.y = __expf(v.y - m);
  v.z = __expf(v.z - m); v.w = __expf(v.w - m);
  float sm = v.x + v.y + v.z + v.w;
  for (int off = 1; off < 64; off <<= 1) sm += __shfl_xor(sm, off);
  if ((tid & 63) == 0) wsum[tid >> 6] = sm;
  __syncthreads();
  sm = wsum[0] + wsum[1] + wsum[2] + wsum[3];
  float inv = 1.f / sm;
  ushort4_t o;
  o[0] = f2bf(v.x * inv); o[1] = f2bf(v.y * inv);
  o[2] = f2bf(v.z * inv); o[3] = f2bf(v.w * inv);
  *(ushort4_t*)(probs + (row << 10) + tid * 4) = o;
}

// ---------------- PV (MFMA) + gating: go[i, h*64+d] = g * sum_j P[h,i,j] vt[h*64+d, j] ----------------
__global__ __launch_bounds__(256) void pv_mfma(const unsigned short* __restrict__ probs,
    const unsigned short* __restrict__ vt, const unsigned short* __restrict__ g,
    unsigned short* __restrict__ go) {
  int h = blockIdx.y, i0 = blockIdx.x * 64;
  __shared__ __align__(16) unsigned short Ps[64][40], Vs[64][40];
  int tid = threadIdx.x, wid = tid >> 6, lane = tid & 63;
  int lrow = lane & 15, lk8 = (lane >> 4) * 8;
  int ar = tid >> 2, ak = (tid & 3) * 8;
  f32x4 acc[4] = {};
  for (int j0 = 0; j0 < NTOK; j0 += 32) {
    *(ushort8_t*)&Ps[ar][ak] = *(const ushort8_t*)(probs + ((size_t)h << 20) + ((size_t)(i0 + ar) << 10) + j0 + ak);
    *(ushort8_t*)&Vs[ar][ak] = *(const ushort8_t*)(vt + (size_t)(h * HD + ar) * NTOK + j0 + ak);
    __syncthreads();
    bf16x8 af = *(bf16x8*)&Ps[wid * 16 + lrow][lk8];
    #pragma unroll
    for (int nb = 0; nb < 4; ++nb) {
      bf16x8 bfr = *(bf16x8*)&Vs[nb * 16 + lrow][lk8];
      acc[nb] = __builtin_amdgcn_mfma_f32_16x16x32_bf16(af, bfr, acc[nb], 0, 0, 0);
    }
    __syncthreads();
  }
  #pragma unroll
  for (int nb = 0; nb < 4; ++nb) {
    #pragma unroll
    for (int r = 0; r < 4; ++r) {
      int grow = i0 + wid * 16 + (lane >> 4) * 4 + r;
      int d = nb * 16 + lrow;
      size_t off = (size_t)grow * CS + h * HD + d;
      float gv = bf2f(g[off]);
      go[off] = f2bf(acc[nb][r] * gv);
    }
  }
}

extern "C" void kernel_launch(void* const* d_in, const int* in_sizes, int n_in,
                              void* d_out, int out_size, void* d_ws, size_t ws_size,
                              hipStream_t stream) {
  const float* s    = (const float*)d_in[0];
  const float* z    = (const float*)d_in[1];
  const float* mask = (const float*)d_in[2];
  const float* nss  = (const float*)d_in[3];
  const float* nsb  = (const float*)d_in[4];
  const float* Wq   = (const float*)d_in[5];
  const float* bq   = (const float*)d_in[6];
  const float* Wk   = (const float*)d_in[7];
  const float* Wv   = (const float*)d_in[8];
  const float* Wg   = (const float*)d_in[9];
  const float* nzs  = (const float*)d_in[10];
  const float* nzb  = (const float*)d_in[11];
  const float* Wz   = (const float*)d_in[12];
  const float* Wo   = (const float*)d_in[13];
  float* out = (float*)d_out;

  const size_t SN = (size_t)NTOK * CS;       // 786432
  const size_t NPAIR = (size_t)NTOK * NTOK;  // 1M
  const size_t WSZ = (size_t)CS * CS;        // 589824

  float* zbuf = (float*)d_ws;                // 12M f32
  float* sbuf = zbuf + NH * NPAIR;           // 12M f32
  unsigned short* sn    = (unsigned short*)(sbuf + NH * NPAIR);
  unsigned short* qb    = sn + SN;
  unsigned short* kb    = qb + SN;
  unsigned short* vtb   = kb + SN;           // [768][1024] transposed
  unsigned short* gb    = vtb + SN;
  unsigned short* gob   = gb + SN;
  unsigned short* probs = gob + SN;          // 12M bf16
  unsigned short* wt    = probs + NH * NPAIR; // 5 x 589824

  ln_s_kernel<<<NTOK, 256, 0, stream>>>(s, nss, nsb, sn);
  cvt_w_kernel<<<dim3(12, 12, 5), 256, 0, stream>>>(Wq, Wk, Wv, Wg, Wo, wt);
  zb_kernel<<<2048, 256, 0, stream>>>(z, nzs, nzb, Wz, zbuf);
  gemm_bf16<<<dim3(12, 16), 256, 0, stream>>>(sn, wt + 0 * WSZ, bq,      qb,  NTOK, CS, CS, GB_BIAS);
  gemm_bf16<<<dim3(12, 16), 256, 0, stream>>>(sn, wt + 1 * WSZ, nullptr, kb,  NTOK, CS, CS, GB_BF16);
  gemm_bf16<<<dim3(12, 16), 256, 0, stream>>>(sn, wt + 2 * WSZ, nullptr, vtb, NTOK, CS, CS, GB_TRANS);
  gemm_bf16<<<dim3(12, 16), 256, 0, stream>>>(sn, wt + 3 * WSZ, nullptr, gb,  NTOK, CS, CS, GB_SIG);
  scores_mfma<<<dim3(16, 16, 12), 256, 0, stream>>>(qb, kb, zbuf, mask, sbuf);
  softmax_kernel<<<NH * NTOK, 256, 0, stream>>>(sbuf, probs);
  pv_mfma<<<dim3(16, 12), 256, 0, stream>>>(probs, vtb, gb, gob);
  gemm_bf16<<<dim3(12, 16), 256, 0, stream>>>(gob, wt + 4 * WSZ, nullptr, out, NTOK, CS, CS, GB_F32);
}

// Round 3
// 374.897 us; speedup vs baseline: 3.2995x; 1.1299x over previous
//
#include <hip/hip_runtime.h>
#include <hip/hip_bf16.h>

#define CS 768
#define NTOK 1024
#define CZ 128
#define NH 12
#define HD 64

typedef __attribute__((ext_vector_type(8))) short bf16x8;
typedef __attribute__((ext_vector_type(4))) float f32x4;
typedef __attribute__((ext_vector_type(8))) unsigned short ushort8_t;
typedef __attribute__((ext_vector_type(4))) unsigned short ushort4_t;

__device__ inline unsigned short f2bf(float f) {
  __hip_bfloat16 h = __float2bfloat16(f);
  return *reinterpret_cast<unsigned short*>(&h);
}
__device__ inline float bf2f(unsigned short u) {
  union { unsigned int i; float f; } c; c.i = ((unsigned int)u) << 16;
  return c.f;
}
__device__ inline unsigned int cvtpk_bf16(float lo, float hi) {
  unsigned int r;
  asm("v_cvt_pk_bf16_f32 %0, %1, %2" : "=v"(r) : "v"(lo), "v"(hi));
  return r;
}

// ---------------- LayerNorm over s: (1024, 768) -> bf16 ----------------
__global__ __launch_bounds__(256) void ln_s_kernel(const float* __restrict__ s,
    const float* __restrict__ sc, const float* __restrict__ bi, unsigned short* __restrict__ sn) {
  int row = blockIdx.x;
  const float* x = s + (size_t)row * CS;
  int tid = threadIdx.x;
  float v0 = x[tid], v1 = x[tid + 256], v2 = x[tid + 512];
  float sum = v0 + v1 + v2;
  float sq  = v0*v0 + v1*v1 + v2*v2;
  for (int off = 1; off < 64; off <<= 1) {
    sum += __shfl_xor(sum, off);
    sq  += __shfl_xor(sq,  off);
  }
  __shared__ float ws1[4], ws2[4];
  if ((tid & 63) == 0) { ws1[tid >> 6] = sum; ws2[tid >> 6] = sq; }
  __syncthreads();
  float S = ws1[0] + ws1[1] + ws1[2] + ws1[3];
  float Q = ws2[0] + ws2[1] + ws2[2] + ws2[3];
  float mu  = S * (1.f / CS);
  float var = Q * (1.f / CS) - mu * mu;
  float rs  = rsqrtf(var + 1e-5f);
  unsigned short* y = sn + (size_t)row * CS;
  y[tid]       = f2bf((v0 - mu) * rs * sc[tid]       + bi[tid]);
  y[tid + 256] = f2bf((v1 - mu) * rs * sc[tid + 256] + bi[tid + 256]);
  y[tid + 512] = f2bf((v2 - mu) * rs * sc[tid + 512] + bi[tid + 512]);
}

// ---------------- transpose+convert 5 weights (768x768 f32) -> bf16 N x K ----------------
__global__ __launch_bounds__(256) void cvt_w_kernel(const float* __restrict__ W0,
    const float* __restrict__ W1, const float* __restrict__ W2,
    const float* __restrict__ W3, const float* __restrict__ W4,
    unsigned short* __restrict__ out) {
  const float* W = blockIdx.z == 0 ? W0 : blockIdx.z == 1 ? W1 :
                   blockIdx.z == 2 ? W2 : blockIdx.z == 3 ? W3 : W4;
  unsigned short* Wt = out + (size_t)blockIdx.z * CS * CS;
  __shared__ float tile[64][65];
  int k0 = blockIdx.x * 64, n0 = blockIdx.y * 64;
  int t = threadIdx.x;
  #pragma unroll
  for (int it = 0; it < 4; ++it) {
    int r = (t >> 4) + it * 16;
    int c = (t & 15) * 4;
    float4 vv = *(const float4*)(W + (size_t)(k0 + r) * CS + n0 + c);
    tile[r][c] = vv.x; tile[r][c+1] = vv.y; tile[r][c+2] = vv.z; tile[r][c+3] = vv.w;
  }
  __syncthreads();
  #pragma unroll
  for (int it = 0; it < 2; ++it) {
    int idx = t + it * 256;
    int n = idx >> 3, k8 = (idx & 7) * 8;
    ushort8_t o;
    #pragma unroll
    for (int e = 0; e < 8; ++e) o[e] = f2bf(tile[k8 + e][n]);
    *(ushort8_t*)(Wt + (size_t)(n0 + n) * CS + k0 + k8) = o;
  }
}

// ---------------- zb: LN(z) @ Wz -> (12, 1024, 1024) fp32 ----------------
__global__ __launch_bounds__(256) void zb_kernel(const float* __restrict__ z,
    const float* __restrict__ gs, const float* __restrict__ gb,
    const float* __restrict__ Wz, float* __restrict__ zb) {
  const int lane = threadIdx.x & 63;
  const int sub  = lane & 15;
  const int slot = lane >> 4;
  const int waveId = blockIdx.x * (blockDim.x >> 6) + (threadIdx.x >> 6);
  const int nWaves = gridDim.x * (blockDim.x >> 6);
  const int cA = sub * 4, cB = 64 + sub * 4;

  float wza[4][12], wzb[4][12];
  float sa[4], sb[4], ba[4], bb[4];
  #pragma unroll
  for (int u = 0; u < 4; ++u) {
    sa[u] = gs[cA + u]; ba[u] = gb[cA + u];
    sb[u] = gs[cB + u]; bb[u] = gb[cB + u];
    #pragma unroll
    for (int h = 0; h < NH; ++h) {
      wza[u][h] = Wz[(cA + u) * NH + h];
      wzb[u][h] = Wz[(cB + u) * NH + h];
    }
  }

  const int NPAIR = NTOK * NTOK;
  const int NQUAD = NPAIR / 4;
  for (int quad = waveId; quad < NQUAD; quad += nWaves) {
    int p = quad * 4 + slot;
    const float* zp = z + (size_t)p * CZ;
    float4 za = *(const float4*)(zp + cA);
    float4 zc = *(const float4*)(zp + cB);
    float zav[4] = {za.x, za.y, za.z, za.w};
    float zbv[4] = {zc.x, zc.y, zc.z, zc.w};

    float sum = 0.f, sq = 0.f;
    #pragma unroll
    for (int u = 0; u < 4; ++u) {
      sum += zav[u] + zbv[u];
      sq = fmaf(zav[u], zav[u], sq);
      sq = fmaf(zbv[u], zbv[u], sq);
    }
    #pragma unroll
    for (int m = 1; m < 16; m <<= 1) {
      sum += __shfl_xor(sum, m);
      sq  += __shfl_xor(sq,  m);
    }
    float mu  = sum * (1.f / CZ);
    float var = sq * (1.f / CZ) - mu * mu;
    float rs  = rsqrtf(var + 1e-5f);

    float acc[NH] = {};
    #pragma unroll
    for (int u = 0; u < 4; ++u) {
      float nva = fmaf((zav[u] - mu) * rs, sa[u], ba[u]);
      float nvb = fmaf((zbv[u] - mu) * rs, sb[u], bb[u]);
      #pragma unroll
      for (int h = 0; h < NH; ++h) {
        acc[h] = fmaf(nva, wza[u][h], acc[h]);
        acc[h] = fmaf(nvb, wzb[u][h], acc[h]);
      }
    }
    #pragma unroll
    for (int h = 0; h < NH; ++h) {
      float t = acc[h];
      #pragma unroll
      for (int m = 1; m < 16; m <<= 1) t += __shfl_xor(t, m);
      if (sub == 0) zb[(size_t)h * NPAIR + p] = t;
    }
  }
}

// ---------------- fused QKVG GEMM: [1024x768] @ [768x3072 sections] ----------------
// Wt rows 0-767: Wq^T, 768-1535: Wk^T, 1536-2303: Wv^T, 2304-3071: Wg^T.
__global__ __launch_bounds__(256) void qkvg_gemm(const unsigned short* __restrict__ A,
    const unsigned short* __restrict__ Wt, const float* __restrict__ bq,
    unsigned short* __restrict__ qb, unsigned short* __restrict__ kb,
    unsigned short* __restrict__ vtb, unsigned short* __restrict__ gbuf) {
  __shared__ __align__(16) unsigned short As[64][40];
  __shared__ __align__(16) unsigned short Bs[64][40];
  int tid = threadIdx.x;
  int wid = tid >> 6, lane = tid & 63;
  int lrow = lane & 15, lk8 = (lane >> 4) * 8;
  int row0 = blockIdx.y * 64, col0 = blockIdx.x * 64;   // col0 in [0,3072)
  int ar = tid >> 2, ak = (tid & 3) * 8;
  f32x4 acc[4] = {};
  for (int k0 = 0; k0 < CS; k0 += 32) {
    *(ushort8_t*)&As[ar][ak] = *(const ushort8_t*)(A  + (size_t)(row0 + ar) * CS + k0 + ak);
    *(ushort8_t*)&Bs[ar][ak] = *(const ushort8_t*)(Wt + (size_t)(col0 + ar) * CS + k0 + ak);
    __syncthreads();
    bf16x8 af = *(bf16x8*)&As[wid * 16 + lrow][lk8];
    #pragma unroll
    for (int nb = 0; nb < 4; ++nb) {
      bf16x8 bfr = *(bf16x8*)&Bs[nb * 16 + lrow][lk8];
      acc[nb] = __builtin_amdgcn_mfma_f32_16x16x32_bf16(af, bfr, acc[nb], 0, 0, 0);
    }
    __syncthreads();
  }
  int sect = col0 / CS;          // 0=q 1=k 2=v 3=g
  int ncol0 = col0 - sect * CS;
  int grow0 = row0 + wid * 16 + (lane >> 4) * 4;
  if (sect == 2) {
    #pragma unroll
    for (int nb = 0; nb < 4; ++nb) {
      int dg = ncol0 + nb * 16 + lrow;
      ushort4_t o;
      #pragma unroll
      for (int r = 0; r < 4; ++r) o[r] = f2bf(acc[nb][r]);
      *(ushort4_t*)(vtb + (size_t)dg * NTOK + grow0) = o;
    }
  } else {
    unsigned short* dst = sect == 0 ? qb : sect == 1 ? kb : gbuf;
    #pragma unroll
    for (int nb = 0; nb < 4; ++nb) {
      int gcol = ncol0 + nb * 16 + lrow;
      float bv = (sect == 0) ? bq[gcol] : 0.f;
      #pragma unroll
      for (int r = 0; r < 4; ++r) {
        float val = acc[nb][r] + bv;
        if (sect == 3) val = 1.f / (1.f + __expf(-val));
        dst[(size_t)(grow0 + r) * CS + gcol] = f2bf(val);
      }
    }
  }
}

// ---------------- fused flash attention: scores + softmax + PV + gating ----------------
// grid (12 heads, 16 i-tiles of 64), 4 waves/block, wave w owns q-rows [i0+16w, i0+16w+16).
// No LDS: all operands direct global->VGPR (K/V tiles served by L1/L2).
__global__ __launch_bounds__(256) void flash_attn(
    const unsigned short* __restrict__ qb, const unsigned short* __restrict__ kb,
    const unsigned short* __restrict__ vtb, const unsigned short* __restrict__ gbuf,
    const float* __restrict__ zbuf, const float* __restrict__ mask,
    unsigned short* __restrict__ gob) {
  const int h = blockIdx.x;
  const int i0 = blockIdx.y * 64;
  const int w = threadIdx.x >> 6, lane = threadIdx.x & 63;
  const int il = lane & 15, g = lane >> 4;
  const int irow = i0 + w * 16 + il;     // this lane's q-row (S^T column)
  const float LOG2E = 1.44269504f;

  // Q as B-fragments (col=il -> q-row, k=d)
  bf16x8 qf0 = *(const bf16x8*)(qb + (size_t)irow * CS + h * HD + g * 8);
  bf16x8 qf1 = *(const bf16x8*)(qb + (size_t)irow * CS + h * HD + 32 + g * 8);

  f32x4 oacc[4] = {};                    // O^T frags, db=0..3; lane holds d=16db+4g+r, col=il
  float mrun = -1e30f, lrun = 0.f;
  const float* zrow = zbuf + ((size_t)h << 20) + ((size_t)irow << 10);

  for (int j0 = 0; j0 < NTOK; j0 += 64) {
    // S^T = K x Q^T : sacc[jb] rows j=16jb+4g+r, col il=q-row
    f32x4 sacc[4] = {};
    #pragma unroll
    for (int jb = 0; jb < 4; ++jb) {
      const unsigned short* kbase = kb + (size_t)(j0 + jb * 16 + il) * CS + h * HD;
      bf16x8 kf0 = *(const bf16x8*)(kbase + g * 8);
      bf16x8 kf1 = *(const bf16x8*)(kbase + 32 + g * 8);
      sacc[jb] = __builtin_amdgcn_mfma_f32_16x16x32_bf16(kf0, qf0, sacc[jb], 0, 0, 0);
      sacc[jb] = __builtin_amdgcn_mfma_f32_16x16x32_bf16(kf1, qf1, sacc[jb], 0, 0, 0);
    }
    // s2 = (qk/8 + zb + maskterm) * log2(e);  lane's 16 j-scores for one q-row
    float s2[16];
    float rmax = -1e30f;
    #pragma unroll
    for (int jb = 0; jb < 4; ++jb) {
      float4 z4 = *(const float4*)(zrow + j0 + jb * 16 + g * 4);
      float4 mk = *(const float4*)(mask + j0 + jb * 16 + g * 4);
      float m0 = (1.f - mk.x) * -1000000.0f;
      float m1 = (1.f - mk.y) * -1000000.0f;
      float m2 = (1.f - mk.z) * -1000000.0f;
      float m3 = (1.f - mk.w) * -1000000.0f;
      s2[jb*4+0] = (fmaf(sacc[jb][0], 0.125f, z4.x) + m0) * LOG2E;
      s2[jb*4+1] = (fmaf(sacc[jb][1], 0.125f, z4.y) + m1) * LOG2E;
      s2[jb*4+2] = (fmaf(sacc[jb][2], 0.125f, z4.z) + m2) * LOG2E;
      s2[jb*4+3] = (fmaf(sacc[jb][3], 0.125f, z4.w) + m3) * LOG2E;
      rmax = fmaxf(rmax, fmaxf(fmaxf(s2[jb*4+0], s2[jb*4+1]), fmaxf(s2[jb*4+2], s2[jb*4+3])));
    }
    rmax = fmaxf(rmax, __shfl_xor(rmax, 16));
    rmax = fmaxf(rmax, __shfl_xor(rmax, 32));
    float mnew = fmaxf(mrun, rmax);
    float scale = exp2f(mrun - mnew);
    float rsum = 0.f;
    unsigned int c0[4], c1[4];
    #pragma unroll
    for (int jb = 0; jb < 4; ++jb) {
      float p0 = exp2f(s2[jb*4+0] - mnew);
      float p1 = exp2f(s2[jb*4+1] - mnew);
      float p2 = exp2f(s2[jb*4+2] - mnew);
      float p3 = exp2f(s2[jb*4+3] - mnew);
      rsum += (p0 + p1) + (p2 + p3);
      c0[jb] = cvtpk_bf16(p0, p1);
      c1[jb] = cvtpk_bf16(p2, p3);
    }
    rsum += __shfl_xor(rsum, 16);
    rsum += __shfl_xor(rsum, 32);
    lrun = fmaf(lrun, scale, rsum);
    mrun = mnew;
    #pragma unroll
    for (int db = 0; db < 4; ++db) {
      oacc[db][0] *= scale; oacc[db][1] *= scale;
      oacc[db][2] *= scale; oacc[db][3] *= scale;
    }
    // redistribute P^T (held j=16jb+4g+r) into PV B-fragments (need k=j_local=8g+0..7)
    #pragma unroll
    for (int js = 0; js < 2; ++js) {
      int srcLo = ((g & 1) << 5) + il;   // source lane group 2*(g&1)
      int srcHi = srcLo + 16;            // source lane group 2*(g&1)+1
      unsigned int a0 = (unsigned int)__shfl((int)c0[2*js],     srcLo);
      unsigned int b0 = (unsigned int)__shfl((int)c0[2*js + 1], srcLo);
      unsigned int a1 = (unsigned int)__shfl((int)c1[2*js],     srcLo);
      unsigned int b1 = (unsigned int)__shfl((int)c1[2*js + 1], srcLo);
      unsigned int a2 = (unsigned int)__shfl((int)c0[2*js],     srcHi);
      unsigned int b2 = (unsigned int)__shfl((int)c0[2*js + 1], srcHi);
      unsigned int a3 = (unsigned int)__shfl((int)c1[2*js],     srcHi);
      unsigned int b3 = (unsigned int)__shfl((int)c1[2*js + 1], srcHi);
      bool hi = (g & 2) != 0;
      union { unsigned int u[4]; bf16x8 v; } pb;
      pb.u[0] = hi ? b0 : a0;
      pb.u[1] = hi ? b1 : a1;
      pb.u[2] = hi ? b2 : a2;
      pb.u[3] = hi ? b3 : a3;
      #pragma unroll
      for (int db = 0; db < 4; ++db) {
        bf16x8 vf = *(const bf16x8*)(vtb + (size_t)(h * HD + db * 16 + il) * NTOK + j0 + js * 32 + g * 8);
        oacc[db] = __builtin_amdgcn_mfma_f32_16x16x32_bf16(vf, pb.v, oacc[db], 0, 0, 0);
      }
    }
  }
  float inv = 1.f / lrun;
  #pragma unroll
  for (int db = 0; db < 4; ++db) {
    size_t off = (size_t)irow * CS + h * HD + db * 16 + g * 4;
    ushort4_t g4 = *(const ushort4_t*)(gbuf + off);
    ushort4_t o4;
    #pragma unroll
    for (int r = 0; r < 4; ++r)
      o4[r] = f2bf(oacc[db][r] * inv * bf2f(g4[r]));
    *(ushort4_t*)(gob + off) = o4;
  }
}

// ---------------- final GEMM: out = gob @ Wo  (f32 out) ----------------
__global__ __launch_bounds__(256) void out_gemm(const unsigned short* __restrict__ A,
    const unsigned short* __restrict__ Bt, float* __restrict__ C) {
  __shared__ __align__(16) unsigned short As[64][40];
  __shared__ __align__(16) unsigned short Bs[64][40];
  int tid = threadIdx.x;
  int wid = tid >> 6, lane = tid & 63;
  int lrow = lane & 15, lk8 = (lane >> 4) * 8;
  int row0 = blockIdx.y * 64, col0 = blockIdx.x * 64;
  int ar = tid >> 2, ak = (tid & 3) * 8;
  f32x4 acc[4] = {};
  for (int k0 = 0; k0 < CS; k0 += 32) {
    *(ushort8_t*)&As[ar][ak] = *(const ushort8_t*)(A  + (size_t)(row0 + ar) * CS + k0 + ak);
    *(ushort8_t*)&Bs[ar][ak] = *(const ushort8_t*)(Bt + (size_t)(col0 + ar) * CS + k0 + ak);
    __syncthreads();
    bf16x8 af = *(bf16x8*)&As[wid * 16 + lrow][lk8];
    #pragma unroll
    for (int nb = 0; nb < 4; ++nb) {
      bf16x8 bfr = *(bf16x8*)&Bs[nb * 16 + lrow][lk8];
      acc[nb] = __builtin_amdgcn_mfma_f32_16x16x32_bf16(af, bfr, acc[nb], 0, 0, 0);
    }
    __syncthreads();
  }
  #pragma unroll
  for (int nb = 0; nb < 4; ++nb) {
    int gcol = col0 + nb * 16 + lrow;
    #pragma unroll
    for (int r = 0; r < 4; ++r) {
      int grow = row0 + wid * 16 + (lane >> 4) * 4 + r;
      C[(size_t)grow * CS + gcol] = acc[nb][r];
    }
  }
}

extern "C" void kernel_launch(void* const* d_in, const int* in_sizes, int n_in,
                              void* d_out, int out_size, void* d_ws, size_t ws_size,
                              hipStream_t stream) {
  const float* s    = (const float*)d_in[0];
  const float* z    = (const float*)d_in[1];
  const float* mask = (const float*)d_in[2];
  const float* nss  = (const float*)d_in[3];
  const float* nsb  = (const float*)d_in[4];
  const float* Wq   = (const float*)d_in[5];
  const float* bq   = (const float*)d_in[6];
  const float* Wk   = (const float*)d_in[7];
  const float* Wv   = (const float*)d_in[8];
  const float* Wg   = (const float*)d_in[9];
  const float* nzs  = (const float*)d_in[10];
  const float* nzb  = (const float*)d_in[11];
  const float* Wz   = (const float*)d_in[12];
  const float* Wo   = (const float*)d_in[13];
  float* out = (float*)d_out;

  const size_t SN = (size_t)NTOK * CS;        // 786432
  const size_t NPAIR = (size_t)NTOK * NTOK;   // 1M
  const size_t WSZ = (size_t)CS * CS;         // 589824

  float* zbuf = (float*)d_ws;                          // 12M f32
  unsigned short* sn  = (unsigned short*)(zbuf + NH * NPAIR);
  unsigned short* qb  = sn  + SN;
  unsigned short* kb  = qb  + SN;
  unsigned short* vtb = kb  + SN;                      // [768][1024] transposed V
  unsigned short* gbuf= vtb + SN;
  unsigned short* gob = gbuf+ SN;
  unsigned short* wt  = gob + SN;                      // 5 x [768][768]

  ln_s_kernel<<<NTOK, 256, 0, stream>>>(s, nss, nsb, sn);
  cvt_w_kernel<<<dim3(12, 12, 5), 256, 0, stream>>>(Wq, Wk, Wv, Wg, Wo, wt);
  zb_kernel<<<2048, 256, 0, stream>>>(z, nzs, nzb, Wz, zbuf);
  qkvg_gemm<<<dim3(48, 16), 256, 0, stream>>>(sn, wt, bq, qb, kb, vtb, gbuf);
  flash_attn<<<dim3(12, 16), 256, 0, stream>>>(qb, kb, vtb, gbuf, zbuf, mask, gob);
  out_gemm<<<dim3(12, 16), 256, 0, stream>>>(gob, wt + 4 * WSZ, out);
}

// Round 4
// 231.596 us; speedup vs baseline: 5.3411x; 1.6188x over previous
//
#include <hip/hip_runtime.h>
#include <hip/hip_bf16.h>

#define CS 768
#define NTOK 1024
#define CZ 128
#define NH 12
#define HD 64

typedef __attribute__((ext_vector_type(8))) short bf16x8;
typedef __attribute__((ext_vector_type(4))) float f32x4;
typedef __attribute__((ext_vector_type(8))) unsigned short ushort8_t;
typedef __attribute__((ext_vector_type(4))) unsigned short ushort4_t;

__device__ inline unsigned short f2bf(float f) {
  __hip_bfloat16 h = __float2bfloat16(f);
  return *reinterpret_cast<unsigned short*>(&h);
}
__device__ inline float bf2f(unsigned short u) {
  union { unsigned int i; float f; } c; c.i = ((unsigned int)u) << 16;
  return c.f;
}
__device__ inline unsigned int cvtpk_bf16(float lo, float hi) {
  unsigned int r;
  asm("v_cvt_pk_bf16_f32 %0, %1, %2" : "=v"(r) : "v"(lo), "v"(hi));
  return r;
}

// ---------------- LayerNorm over s: (1024, 768) -> bf16 ----------------
__global__ __launch_bounds__(256) void ln_s_kernel(const float* __restrict__ s,
    const float* __restrict__ sc, const float* __restrict__ bi, unsigned short* __restrict__ sn) {
  int row = blockIdx.x;
  const float* x = s + (size_t)row * CS;
  int tid = threadIdx.x;
  float v0 = x[tid], v1 = x[tid + 256], v2 = x[tid + 512];
  float sum = v0 + v1 + v2;
  float sq  = v0*v0 + v1*v1 + v2*v2;
  for (int off = 1; off < 64; off <<= 1) {
    sum += __shfl_xor(sum, off);
    sq  += __shfl_xor(sq,  off);
  }
  __shared__ float ws1[4], ws2[4];
  if ((tid & 63) == 0) { ws1[tid >> 6] = sum; ws2[tid >> 6] = sq; }
  __syncthreads();
  float S = ws1[0] + ws1[1] + ws1[2] + ws1[3];
  float Q = ws2[0] + ws2[1] + ws2[2] + ws2[3];
  float mu  = S * (1.f / CS);
  float var = Q * (1.f / CS) - mu * mu;
  float rs  = rsqrtf(var + 1e-5f);
  unsigned short* y = sn + (size_t)row * CS;
  y[tid]       = f2bf((v0 - mu) * rs * sc[tid]       + bi[tid]);
  y[tid + 256] = f2bf((v1 - mu) * rs * sc[tid + 256] + bi[tid + 256]);
  y[tid + 512] = f2bf((v2 - mu) * rs * sc[tid + 512] + bi[tid + 512]);
}

// ---------------- transpose+convert 5 weights (768x768 f32) -> bf16 N x K ----------------
__global__ __launch_bounds__(256) void cvt_w_kernel(const float* __restrict__ W0,
    const float* __restrict__ W1, const float* __restrict__ W2,
    const float* __restrict__ W3, const float* __restrict__ W4,
    unsigned short* __restrict__ out) {
  const float* W = blockIdx.z == 0 ? W0 : blockIdx.z == 1 ? W1 :
                   blockIdx.z == 2 ? W2 : blockIdx.z == 3 ? W3 : W4;
  unsigned short* Wt = out + (size_t)blockIdx.z * CS * CS;
  __shared__ float tile[64][65];
  int k0 = blockIdx.x * 64, n0 = blockIdx.y * 64;
  int t = threadIdx.x;
  #pragma unroll
  for (int it = 0; it < 4; ++it) {
    int r = (t >> 4) + it * 16;
    int c = (t & 15) * 4;
    float4 vv = *(const float4*)(W + (size_t)(k0 + r) * CS + n0 + c);
    tile[r][c] = vv.x; tile[r][c+1] = vv.y; tile[r][c+2] = vv.z; tile[r][c+3] = vv.w;
  }
  __syncthreads();
  #pragma unroll
  for (int it = 0; it < 2; ++it) {
    int idx = t + it * 256;
    int n = idx >> 3, k8 = (idx & 7) * 8;
    ushort8_t o;
    #pragma unroll
    for (int e = 0; e < 8; ++e) o[e] = f2bf(tile[k8 + e][n]);
    *(ushort8_t*)(Wt + (size_t)(n0 + n) * CS + k0 + k8) = o;
  }
}

// ---------------- zb (MFMA): zbuf[h][p] = (LN(z[p]) @ Wz[:,h] + maskterm) * log2e ----------------
// Wave handles 16 pairs x 16 heads (12 valid). LN fused in-register; split-bf16 for accuracy.
__global__ __launch_bounds__(256) void zb_mfma(const float* __restrict__ z,
    const float* __restrict__ gs, const float* __restrict__ gb,
    const float* __restrict__ Wz, const float* __restrict__ mask,
    float* __restrict__ zbuf) {
  const int lane = threadIdx.x & 63;
  const int il = lane & 15;       // A-row / C-col (head) index
  const int qg = lane >> 4;       // k-group; C-row group
  const size_t NPAIR = (size_t)NTOK * NTOK;

  // Preload per-lane LN scale/bias for channels c = 32m + 8qg + e, and split-bf16 Wz B-frags.
  float sc[32], bi[32];
  bf16x8 whi[4], wlo[4];
  #pragma unroll
  for (int m = 0; m < 4; ++m) {
    union { unsigned short u[8]; bf16x8 v; } hi, lo;
    #pragma unroll
    for (int e = 0; e < 8; ++e) {
      int c = 32 * m + 8 * qg + e;
      sc[m * 8 + e] = gs[c];
      bi[m * 8 + e] = gb[c];
      float w = (il < NH) ? Wz[c * NH + il] : 0.f;
      unsigned short h = f2bf(w);
      hi.u[e] = h;
      lo.u[e] = f2bf(w - bf2f(h));
    }
    whi[m] = hi.v; wlo[m] = lo.v;
  }

  const int wave = blockIdx.x * 4 + (threadIdx.x >> 6);
  const int nWaves = gridDim.x * 4;
  for (size_t p0 = (size_t)wave * 16; p0 < NPAIR; p0 += (size_t)nWaves * 16) {
    const float* zrow = z + (p0 + il) * CZ;
    float zv[32];
    #pragma unroll
    for (int m = 0; m < 4; ++m) {
      float4 a = *(const float4*)(zrow + 32 * m + 8 * qg);
      float4 b = *(const float4*)(zrow + 32 * m + 8 * qg + 4);
      zv[m*8+0] = a.x; zv[m*8+1] = a.y; zv[m*8+2] = a.z; zv[m*8+3] = a.w;
      zv[m*8+4] = b.x; zv[m*8+5] = b.y; zv[m*8+6] = b.z; zv[m*8+7] = b.w;
    }
    float sum = 0.f, sq = 0.f;
    #pragma unroll
    for (int e = 0; e < 32; ++e) { sum += zv[e]; sq = fmaf(zv[e], zv[e], sq); }
    sum += __shfl_xor(sum, 16); sum += __shfl_xor(sum, 32);
    sq  += __shfl_xor(sq,  16); sq  += __shfl_xor(sq,  32);
    float mu  = sum * (1.f / CZ);
    float var = sq * (1.f / CZ) - mu * mu;
    float rs  = rsqrtf(var + 1e-5f);

    bf16x8 ahi[4], alo[4];
    #pragma unroll
    for (int m = 0; m < 4; ++m) {
      union { unsigned short u[8]; bf16x8 v; } hi, lo;
      #pragma unroll
      for (int e = 0; e < 8; ++e) {
        float nv = fmaf((zv[m*8+e] - mu) * rs, sc[m*8+e], bi[m*8+e]);
        unsigned short h = f2bf(nv);
        hi.u[e] = h;
        lo.u[e] = f2bf(nv - bf2f(h));
      }
      ahi[m] = hi.v; alo[m] = lo.v;
    }
    f32x4 acc = {};
    #pragma unroll
    for (int m = 0; m < 4; ++m) {
      acc = __builtin_amdgcn_mfma_f32_16x16x32_bf16(ahi[m], whi[m], acc, 0, 0, 0);
      acc = __builtin_amdgcn_mfma_f32_16x16x32_bf16(alo[m], whi[m], acc, 0, 0, 0);
      acc = __builtin_amdgcn_mfma_f32_16x16x32_bf16(ahi[m], wlo[m], acc, 0, 0, 0);
    }
    if (il < NH) {
      int j0 = (int)(p0 & (NTOK - 1)) + 4 * qg;     // j index of acc[0] (tile never crosses row end)
      float4 mk = *(const float4*)(mask + j0);
      float4 o;
      o.x = (acc[0] + (1.f - mk.x) * -1000000.0f) * 1.44269504f;
      o.y = (acc[1] + (1.f - mk.y) * -1000000.0f) * 1.44269504f;
      o.z = (acc[2] + (1.f - mk.z) * -1000000.0f) * 1.44269504f;
      o.w = (acc[3] + (1.f - mk.w) * -1000000.0f) * 1.44269504f;
      *(float4*)(zbuf + (size_t)il * NPAIR + p0 + 4 * qg) = o;
    }
  }
}

// ---------------- fused QKVG GEMM: [1024x768] @ [768x3072 sections] ----------------
__global__ __launch_bounds__(256) void qkvg_gemm(const unsigned short* __restrict__ A,
    const unsigned short* __restrict__ Wt, const float* __restrict__ bq,
    unsigned short* __restrict__ qb, unsigned short* __restrict__ kb,
    unsigned short* __restrict__ vtb, unsigned short* __restrict__ gbuf) {
  __shared__ __align__(16) unsigned short As[64][40];
  __shared__ __align__(16) unsigned short Bs[64][40];
  int tid = threadIdx.x;
  int wid = tid >> 6, lane = tid & 63;
  int lrow = lane & 15, lk8 = (lane >> 4) * 8;
  int row0 = blockIdx.y * 64, col0 = blockIdx.x * 64;   // col0 in [0,3072)
  int ar = tid >> 2, ak = (tid & 3) * 8;
  f32x4 acc[4] = {};
  for (int k0 = 0; k0 < CS; k0 += 32) {
    *(ushort8_t*)&As[ar][ak] = *(const ushort8_t*)(A  + (size_t)(row0 + ar) * CS + k0 + ak);
    *(ushort8_t*)&Bs[ar][ak] = *(const ushort8_t*)(Wt + (size_t)(col0 + ar) * CS + k0 + ak);
    __syncthreads();
    bf16x8 af = *(bf16x8*)&As[wid * 16 + lrow][lk8];
    #pragma unroll
    for (int nb = 0; nb < 4; ++nb) {
      bf16x8 bfr = *(bf16x8*)&Bs[nb * 16 + lrow][lk8];
      acc[nb] = __builtin_amdgcn_mfma_f32_16x16x32_bf16(af, bfr, acc[nb], 0, 0, 0);
    }
    __syncthreads();
  }
  int sect = col0 / CS;          // 0=q 1=k 2=v 3=g
  int ncol0 = col0 - sect * CS;
  int grow0 = row0 + wid * 16 + (lane >> 4) * 4;
  if (sect == 2) {
    #pragma unroll
    for (int nb = 0; nb < 4; ++nb) {
      int dg = ncol0 + nb * 16 + lrow;
      ushort4_t o;
      #pragma unroll
      for (int r = 0; r < 4; ++r) o[r] = f2bf(acc[nb][r]);
      *(ushort4_t*)(vtb + (size_t)dg * NTOK + grow0) = o;
    }
  } else {
    unsigned short* dst = sect == 0 ? qb : sect == 1 ? kb : gbuf;
    #pragma unroll
    for (int nb = 0; nb < 4; ++nb) {
      int gcol = ncol0 + nb * 16 + lrow;
      float bv = (sect == 0) ? bq[gcol] : 0.f;
      #pragma unroll
      for (int r = 0; r < 4; ++r) {
        float val = acc[nb][r] + bv;
        if (sect == 3) val = 1.f / (1.f + __expf(-val));
        dst[(size_t)(grow0 + r) * CS + gcol] = f2bf(val);
      }
    }
  }
}

// ---------------- fused flash attention: scores + softmax + PV + gating ----------------
// zbuf already contains (zb + maskterm) * log2e.
__global__ __launch_bounds__(256) void flash_attn(
    const unsigned short* __restrict__ qb, const unsigned short* __restrict__ kb,
    const unsigned short* __restrict__ vtb, const unsigned short* __restrict__ gbuf,
    const float* __restrict__ zbuf, unsigned short* __restrict__ gob) {
  const int h = blockIdx.x;
  const int i0 = blockIdx.y * 64;
  const int w = threadIdx.x >> 6, lane = threadIdx.x & 63;
  const int il = lane & 15, g = lane >> 4;
  const int irow = i0 + w * 16 + il;     // this lane's q-row (S^T column)
  const float QKS = 0.125f * 1.44269504f;

  bf16x8 qf0 = *(const bf16x8*)(qb + (size_t)irow * CS + h * HD + g * 8);
  bf16x8 qf1 = *(const bf16x8*)(qb + (size_t)irow * CS + h * HD + 32 + g * 8);

  f32x4 oacc[4] = {};
  float mrun = -1e30f, lrun = 0.f;
  const float* zrow = zbuf + ((size_t)h << 20) + ((size_t)irow << 10);

  for (int j0 = 0; j0 < NTOK; j0 += 64) {
    f32x4 sacc[4] = {};
    #pragma unroll
    for (int jb = 0; jb < 4; ++jb) {
      const unsigned short* kbase = kb + (size_t)(j0 + jb * 16 + il) * CS + h * HD;
      bf16x8 kf0 = *(const bf16x8*)(kbase + g * 8);
      bf16x8 kf1 = *(const bf16x8*)(kbase + 32 + g * 8);
      sacc[jb] = __builtin_amdgcn_mfma_f32_16x16x32_bf16(kf0, qf0, sacc[jb], 0, 0, 0);
      sacc[jb] = __builtin_amdgcn_mfma_f32_16x16x32_bf16(kf1, qf1, sacc[jb], 0, 0, 0);
    }
    float s2[16];
    float rmax = -1e30f;
    #pragma unroll
    for (int jb = 0; jb < 4; ++jb) {
      float4 z4 = *(const float4*)(zrow + j0 + jb * 16 + g * 4);
      s2[jb*4+0] = fmaf(sacc[jb][0], QKS, z4.x);
      s2[jb*4+1] = fmaf(sacc[jb][1], QKS, z4.y);
      s2[jb*4+2] = fmaf(sacc[jb][2], QKS, z4.z);
      s2[jb*4+3] = fmaf(sacc[jb][3], QKS, z4.w);
      rmax = fmaxf(rmax, fmaxf(fmaxf(s2[jb*4+0], s2[jb*4+1]), fmaxf(s2[jb*4+2], s2[jb*4+3])));
    }
    rmax = fmaxf(rmax, __shfl_xor(rmax, 16));
    rmax = fmaxf(rmax, __shfl_xor(rmax, 32));
    float mnew = fmaxf(mrun, rmax);
    float scale = exp2f(mrun - mnew);
    float rsum = 0.f;
    unsigned int c0[4], c1[4];
    #pragma unroll
    for (int jb = 0; jb < 4; ++jb) {
      float p0 = exp2f(s2[jb*4+0] - mnew);
      float p1 = exp2f(s2[jb*4+1] - mnew);
      float p2 = exp2f(s2[jb*4+2] - mnew);
      float p3 = exp2f(s2[jb*4+3] - mnew);
      rsum += (p0 + p1) + (p2 + p3);
      c0[jb] = cvtpk_bf16(p0, p1);
      c1[jb] = cvtpk_bf16(p2, p3);
    }
    rsum += __shfl_xor(rsum, 16);
    rsum += __shfl_xor(rsum, 32);
    lrun = fmaf(lrun, scale, rsum);
    mrun = mnew;
    #pragma unroll
    for (int db = 0; db < 4; ++db) {
      oacc[db][0] *= scale; oacc[db][1] *= scale;
      oacc[db][2] *= scale; oacc[db][3] *= scale;
    }
    #pragma unroll
    for (int js = 0; js < 2; ++js) {
      int srcLo = ((g & 1) << 5) + il;
      int srcHi = srcLo + 16;
      unsigned int a0 = (unsigned int)__shfl((int)c0[2*js],     srcLo);
      unsigned int b0 = (unsigned int)__shfl((int)c0[2*js + 1], srcLo);
      unsigned int a1 = (unsigned int)__shfl((int)c1[2*js],     srcLo);
      unsigned int b1 = (unsigned int)__shfl((int)c1[2*js + 1], srcLo);
      unsigned int a2 = (unsigned int)__shfl((int)c0[2*js],     srcHi);
      unsigned int b2 = (unsigned int)__shfl((int)c0[2*js + 1], srcHi);
      unsigned int a3 = (unsigned int)__shfl((int)c1[2*js],     srcHi);
      unsigned int b3 = (unsigned int)__shfl((int)c1[2*js + 1], srcHi);
      bool hi = (g & 2) != 0;
      union { unsigned int u[4]; bf16x8 v; } pb;
      pb.u[0] = hi ? b0 : a0;
      pb.u[1] = hi ? b1 : a1;
      pb.u[2] = hi ? b2 : a2;
      pb.u[3] = hi ? b3 : a3;
      #pragma unroll
      for (int db = 0; db < 4; ++db) {
        bf16x8 vf = *(const bf16x8*)(vtb + (size_t)(h * HD + db * 16 + il) * NTOK + j0 + js * 32 + g * 8);
        oacc[db] = __builtin_amdgcn_mfma_f32_16x16x32_bf16(vf, pb.v, oacc[db], 0, 0, 0);
      }
    }
  }
  float inv = 1.f / lrun;
  #pragma unroll
  for (int db = 0; db < 4; ++db) {
    size_t off = (size_t)irow * CS + h * HD + db * 16 + g * 4;
    ushort4_t g4 = *(const ushort4_t*)(gbuf + off);
    ushort4_t o4;
    #pragma unroll
    for (int r = 0; r < 4; ++r)
      o4[r] = f2bf(oacc[db][r] * inv * bf2f(g4[r]));
    *(ushort4_t*)(gob + off) = o4;
  }
}

// ---------------- final GEMM: out = gob @ Wo  (f32 out) ----------------
__global__ __launch_bounds__(256) void out_gemm(const unsigned short* __restrict__ A,
    const unsigned short* __restrict__ Bt, float* __restrict__ C) {
  __shared__ __align__(16) unsigned short As[64][40];
  __shared__ __align__(16) unsigned short Bs[64][40];
  int tid = threadIdx.x;
  int wid = tid >> 6, lane = tid & 63;
  int lrow = lane & 15, lk8 = (lane >> 4) * 8;
  int row0 = blockIdx.y * 64, col0 = blockIdx.x * 64;
  int ar = tid >> 2, ak = (tid & 3) * 8;
  f32x4 acc[4] = {};
  for (int k0 = 0; k0 < CS; k0 += 32) {
    *(ushort8_t*)&As[ar][ak] = *(const ushort8_t*)(A  + (size_t)(row0 + ar) * CS + k0 + ak);
    *(ushort8_t*)&Bs[ar][ak] = *(const ushort8_t*)(Bt + (size_t)(col0 + ar) * CS + k0 + ak);
    __syncthreads();
    bf16x8 af = *(bf16x8*)&As[wid * 16 + lrow][lk8];
    #pragma unroll
    for (int nb = 0; nb < 4; ++nb) {
      bf16x8 bfr = *(bf16x8*)&Bs[nb * 16 + lrow][lk8];
      acc[nb] = __builtin_amdgcn_mfma_f32_16x16x32_bf16(af, bfr, acc[nb], 0, 0, 0);
    }
    __syncthreads();
  }
  #pragma unroll
  for (int nb = 0; nb < 4; ++nb) {
    int gcol = col0 + nb * 16 + lrow;
    #pragma unroll
    for (int r = 0; r < 4; ++r) {
      int grow = row0 + wid * 16 + (lane >> 4) * 4 + r;
      C[(size_t)grow * CS + gcol] = acc[nb][r];
    }
  }
}

extern "C" void kernel_launch(void* const* d_in, const int* in_sizes, int n_in,
                              void* d_out, int out_size, void* d_ws, size_t ws_size,
                              hipStream_t stream) {
  const float* s    = (const float*)d_in[0];
  const float* z    = (const float*)d_in[1];
  const float* mask = (const float*)d_in[2];
  const float* nss  = (const float*)d_in[3];
  const float* nsb  = (const float*)d_in[4];
  const float* Wq   = (const float*)d_in[5];
  const float* bq   = (const float*)d_in[6];
  const float* Wk   = (const float*)d_in[7];
  const float* Wv   = (const float*)d_in[8];
  const float* Wg   = (const float*)d_in[9];
  const float* nzs  = (const float*)d_in[10];
  const float* nzb  = (const float*)d_in[11];
  const float* Wz   = (const float*)d_in[12];
  const float* Wo   = (const float*)d_in[13];
  float* out = (float*)d_out;

  const size_t SN = (size_t)NTOK * CS;        // 786432
  const size_t NPAIR = (size_t)NTOK * NTOK;   // 1M
  const size_t WSZ = (size_t)CS * CS;         // 589824

  float* zbuf = (float*)d_ws;                          // 12M f32
  unsigned short* sn  = (unsigned short*)(zbuf + NH * NPAIR);
  unsigned short* qb  = sn  + SN;
  unsigned short* kb  = qb  + SN;
  unsigned short* vtb = kb  + SN;                      // [768][1024] transposed V
  unsigned short* gbuf= vtb + SN;
  unsigned short* gob = gbuf+ SN;
  unsigned short* wt  = gob + SN;                      // 5 x [768][768]

  ln_s_kernel<<<NTOK, 256, 0, stream>>>(s, nss, nsb, sn);
  cvt_w_kernel<<<dim3(12, 12, 5), 256, 0, stream>>>(Wq, Wk, Wv, Wg, Wo, wt);
  zb_mfma<<<2048, 256, 0, stream>>>(z, nzs, nzb, Wz, mask, zbuf);
  qkvg_gemm<<<dim3(48, 16), 256, 0, stream>>>(sn, wt, bq, qb, kb, vtb, gbuf);
  flash_attn<<<dim3(12, 16), 256, 0, stream>>>(qb, kb, vtb, gbuf, zbuf, gob);
  out_gemm<<<dim3(12, 16), 256, 0, stream>>>(gob, wt + 4 * WSZ, out);
}

// Round 5
// 203.469 us; speedup vs baseline: 6.0795x; 1.1382x over previous
//
#include <hip/hip_runtime.h>
#include <hip/hip_bf16.h>

#define CS 768
#define NTOK 1024
#define CZ 128
#define NH 12
#define HD 64
#define NZB 2048          // zb blocks in the heterogeneous kernel
#define JC 4              // flash j-split chunks

typedef __attribute__((ext_vector_type(8))) short bf16x8;
typedef __attribute__((ext_vector_type(4))) float f32x4;
typedef __attribute__((ext_vector_type(8))) unsigned short ushort8_t;
typedef __attribute__((ext_vector_type(4))) unsigned short ushort4_t;

__device__ inline unsigned short f2bf(float f) {
  __hip_bfloat16 h = __float2bfloat16(f);
  return *reinterpret_cast<unsigned short*>(&h);
}
__device__ inline float bf2f(unsigned short u) {
  union { unsigned int i; float f; } c; c.i = ((unsigned int)u) << 16;
  return c.f;
}
__device__ inline unsigned int cvtpk_bf16(float lo, float hi) {
  unsigned int r;
  asm("v_cvt_pk_bf16_f32 %0, %1, %2" : "=v"(r) : "v"(lo), "v"(hi));
  return r;
}

// ---------------- prep: LN(s)->bf16  +  transpose/convert 5 weights ----------------
__global__ __launch_bounds__(256) void prep_kernel(const float* __restrict__ s,
    const float* __restrict__ sc, const float* __restrict__ bi, unsigned short* __restrict__ sn,
    const float* __restrict__ W0, const float* __restrict__ W1, const float* __restrict__ W2,
    const float* __restrict__ W3, const float* __restrict__ W4, unsigned short* __restrict__ wt) {
  __shared__ float tile[64][65];
  int tid = threadIdx.x;
  if (blockIdx.x < NTOK) {
    int row = blockIdx.x;
    const float* x = s + (size_t)row * CS;
    float v0 = x[tid], v1 = x[tid + 256], v2 = x[tid + 512];
    float sum = v0 + v1 + v2;
    float sq  = v0*v0 + v1*v1 + v2*v2;
    for (int off = 1; off < 64; off <<= 1) {
      sum += __shfl_xor(sum, off);
      sq  += __shfl_xor(sq,  off);
    }
    __shared__ float ws1[4], ws2[4];
    if ((tid & 63) == 0) { ws1[tid >> 6] = sum; ws2[tid >> 6] = sq; }
    __syncthreads();
    float S = ws1[0] + ws1[1] + ws1[2] + ws1[3];
    float Q = ws2[0] + ws2[1] + ws2[2] + ws2[3];
    float mu  = S * (1.f / CS);
    float var = Q * (1.f / CS) - mu * mu;
    float rs  = rsqrtf(var + 1e-5f);
    unsigned short* y = sn + (size_t)row * CS;
    y[tid]       = f2bf((v0 - mu) * rs * sc[tid]       + bi[tid]);
    y[tid + 256] = f2bf((v1 - mu) * rs * sc[tid + 256] + bi[tid + 256]);
    y[tid + 512] = f2bf((v2 - mu) * rs * sc[tid + 512] + bi[tid + 512]);
  } else {
    int bz = blockIdx.x - NTOK;           // [0, 720)
    int w = bz / 144, rem = bz % 144;
    int kt = rem % 12, nt = rem / 12;
    const float* W = w == 0 ? W0 : w == 1 ? W1 : w == 2 ? W2 : w == 3 ? W3 : W4;
    unsigned short* Wt = wt + (size_t)w * CS * CS;
    int k0 = kt * 64, n0 = nt * 64;
    #pragma unroll
    for (int it = 0; it < 4; ++it) {
      int r = (tid >> 4) + it * 16;
      int c = (tid & 15) * 4;
      float4 vv = *(const float4*)(W + (size_t)(k0 + r) * CS + n0 + c);
      tile[r][c] = vv.x; tile[r][c+1] = vv.y; tile[r][c+2] = vv.z; tile[r][c+3] = vv.w;
    }
    __syncthreads();
    #pragma unroll
    for (int it = 0; it < 2; ++it) {
      int idx = tid + it * 256;
      int n = idx >> 3, k8 = (idx & 7) * 8;
      ushort8_t o;
      #pragma unroll
      for (int e = 0; e < 8; ++e) o[e] = f2bf(tile[k8 + e][n]);
      *(ushort8_t*)(Wt + (size_t)(n0 + n) * CS + k0 + k8) = o;
    }
  }
}

// ---------------- heterogeneous: zb (MFMA, blocks 0..NZB) + qkvg GEMM (blocks NZB..) ----------------
__global__ __launch_bounds__(256) void zbqkvg_kernel(const float* __restrict__ z,
    const float* __restrict__ gs, const float* __restrict__ gb,
    const float* __restrict__ Wz, const float* __restrict__ mask, float* __restrict__ zbuf,
    const unsigned short* __restrict__ A, const unsigned short* __restrict__ Wt,
    const float* __restrict__ bq, unsigned short* __restrict__ qb,
    unsigned short* __restrict__ kb, unsigned short* __restrict__ vtb,
    unsigned short* __restrict__ gbuf) {
  __shared__ __align__(16) unsigned short As[64][40];
  __shared__ __align__(16) unsigned short Bs[64][40];
  int tid = threadIdx.x;
  if (blockIdx.x < NZB) {
    // ---- zb path ----
    const int lane = tid & 63;
    const int il = lane & 15;
    const int qg = lane >> 4;
    const size_t NPAIR = (size_t)NTOK * NTOK;
    float sc[32], bi[32];
    bf16x8 whi[4], wlo[4];
    #pragma unroll
    for (int m = 0; m < 4; ++m) {
      union { unsigned short u[8]; bf16x8 v; } hi, lo;
      #pragma unroll
      for (int e = 0; e < 8; ++e) {
        int c = 32 * m + 8 * qg + e;
        sc[m * 8 + e] = gs[c];
        bi[m * 8 + e] = gb[c];
        float w = (il < NH) ? Wz[c * NH + il] : 0.f;
        unsigned short h = f2bf(w);
        hi.u[e] = h;
        lo.u[e] = f2bf(w - bf2f(h));
      }
      whi[m] = hi.v; wlo[m] = lo.v;
    }
    const int wave = blockIdx.x * 4 + (tid >> 6);
    const int nWaves = NZB * 4;
    for (size_t p0 = (size_t)wave * 16; p0 < NPAIR; p0 += (size_t)nWaves * 16) {
      const float* zrow = z + (p0 + il) * CZ;
      float zv[32];
      #pragma unroll
      for (int m = 0; m < 4; ++m) {
        float4 a = *(const float4*)(zrow + 32 * m + 8 * qg);
        float4 b = *(const float4*)(zrow + 32 * m + 8 * qg + 4);
        zv[m*8+0] = a.x; zv[m*8+1] = a.y; zv[m*8+2] = a.z; zv[m*8+3] = a.w;
        zv[m*8+4] = b.x; zv[m*8+5] = b.y; zv[m*8+6] = b.z; zv[m*8+7] = b.w;
      }
      float sum = 0.f, sq = 0.f;
      #pragma unroll
      for (int e = 0; e < 32; ++e) { sum += zv[e]; sq = fmaf(zv[e], zv[e], sq); }
      sum += __shfl_xor(sum, 16); sum += __shfl_xor(sum, 32);
      sq  += __shfl_xor(sq,  16); sq  += __shfl_xor(sq,  32);
      float mu  = sum * (1.f / CZ);
      float var = sq * (1.f / CZ) - mu * mu;
      float rs  = rsqrtf(var + 1e-5f);
      bf16x8 ahi[4], alo[4];
      #pragma unroll
      for (int m = 0; m < 4; ++m) {
        union { unsigned short u[8]; bf16x8 v; } hi, lo;
        #pragma unroll
        for (int e = 0; e < 8; ++e) {
          float nv = fmaf((zv[m*8+e] - mu) * rs, sc[m*8+e], bi[m*8+e]);
          unsigned short h = f2bf(nv);
          hi.u[e] = h;
          lo.u[e] = f2bf(nv - bf2f(h));
        }
        ahi[m] = hi.v; alo[m] = lo.v;
      }
      f32x4 acc = {};
      #pragma unroll
      for (int m = 0; m < 4; ++m) {
        acc = __builtin_amdgcn_mfma_f32_16x16x32_bf16(ahi[m], whi[m], acc, 0, 0, 0);
        acc = __builtin_amdgcn_mfma_f32_16x16x32_bf16(alo[m], whi[m], acc, 0, 0, 0);
        acc = __builtin_amdgcn_mfma_f32_16x16x32_bf16(ahi[m], wlo[m], acc, 0, 0, 0);
      }
      if (il < NH) {
        int j0 = (int)(p0 & (NTOK - 1)) + 4 * qg;
        float4 mk = *(const float4*)(mask + j0);
        float4 o;
        o.x = (acc[0] + (1.f - mk.x) * -1000000.0f) * 1.44269504f;
        o.y = (acc[1] + (1.f - mk.y) * -1000000.0f) * 1.44269504f;
        o.z = (acc[2] + (1.f - mk.z) * -1000000.0f) * 1.44269504f;
        o.w = (acc[3] + (1.f - mk.w) * -1000000.0f) * 1.44269504f;
        *(float4*)(zbuf + (size_t)il * NPAIR + p0 + 4 * qg) = o;
      }
    }
  } else {
    // ---- qkvg path ----
    int bx = blockIdx.x - NZB;           // [0, 768)
    int wid = tid >> 6, lane = tid & 63;
    int lrow = lane & 15, lk8 = (lane >> 4) * 8;
    int row0 = (bx / 48) * 64, col0 = (bx % 48) * 64;   // col0 in [0,3072)
    int ar = tid >> 2, ak = (tid & 3) * 8;
    f32x4 acc[4] = {};
    for (int k0 = 0; k0 < CS; k0 += 32) {
      *(ushort8_t*)&As[ar][ak] = *(const ushort8_t*)(A  + (size_t)(row0 + ar) * CS + k0 + ak);
      *(ushort8_t*)&Bs[ar][ak] = *(const ushort8_t*)(Wt + (size_t)(col0 + ar) * CS + k0 + ak);
      __syncthreads();
      bf16x8 af = *(bf16x8*)&As[wid * 16 + lrow][lk8];
      #pragma unroll
      for (int nb = 0; nb < 4; ++nb) {
        bf16x8 bfr = *(bf16x8*)&Bs[nb * 16 + lrow][lk8];
        acc[nb] = __builtin_amdgcn_mfma_f32_16x16x32_bf16(af, bfr, acc[nb], 0, 0, 0);
      }
      __syncthreads();
    }
    int sect = col0 / CS;          // 0=q 1=k 2=v 3=g
    int ncol0 = col0 - sect * CS;
    int grow0 = row0 + wid * 16 + (lane >> 4) * 4;
    if (sect == 2) {
      #pragma unroll
      for (int nb = 0; nb < 4; ++nb) {
        int dg = ncol0 + nb * 16 + lrow;
        ushort4_t o;
        #pragma unroll
        for (int r = 0; r < 4; ++r) o[r] = f2bf(acc[nb][r]);
        *(ushort4_t*)(vtb + (size_t)dg * NTOK + grow0) = o;
      }
    } else {
      unsigned short* dst = sect == 0 ? qb : sect == 1 ? kb : gbuf;
      #pragma unroll
      for (int nb = 0; nb < 4; ++nb) {
        int gcol = ncol0 + nb * 16 + lrow;
        float bv = (sect == 0) ? bq[gcol] : 0.f;
        #pragma unroll
        for (int r = 0; r < 4; ++r) {
          float val = acc[nb][r] + bv;
          if (sect == 3) val = 1.f / (1.f + __expf(-val));
          dst[(size_t)(grow0 + r) * CS + gcol] = f2bf(val);
        }
      }
    }
  }
}

// ---------------- flash partial: j-chunk flash attention, writes O-partial + (m,l) ----------------
__global__ __launch_bounds__(256) void flash_part(
    const unsigned short* __restrict__ qb, const unsigned short* __restrict__ kb,
    const unsigned short* __restrict__ vtb, const float* __restrict__ zbuf,
    float* __restrict__ Opart, float2* __restrict__ ml) {
  const int h = blockIdx.x;
  const int i0 = blockIdx.y * 64;
  const int jc = blockIdx.z;
  const int w = threadIdx.x >> 6, lane = threadIdx.x & 63;
  const int il = lane & 15, g = lane >> 4;
  const int irow = i0 + w * 16 + il;
  const float QKS = 0.125f * 1.44269504f;

  bf16x8 qf0 = *(const bf16x8*)(qb + (size_t)irow * CS + h * HD + g * 8);
  bf16x8 qf1 = *(const bf16x8*)(qb + (size_t)irow * CS + h * HD + 32 + g * 8);

  f32x4 oacc[4] = {};
  float mrun = -1e30f, lrun = 0.f;
  const float* zrow = zbuf + ((size_t)h << 20) + ((size_t)irow << 10);

  const int jlo = jc * (NTOK / JC), jhi = jlo + (NTOK / JC);
  for (int j0 = jlo; j0 < jhi; j0 += 64) {
    f32x4 sacc[4] = {};
    #pragma unroll
    for (int jb = 0; jb < 4; ++jb) {
      const unsigned short* kbase = kb + (size_t)(j0 + jb * 16 + il) * CS + h * HD;
      bf16x8 kf0 = *(const bf16x8*)(kbase + g * 8);
      bf16x8 kf1 = *(const bf16x8*)(kbase + 32 + g * 8);
      sacc[jb] = __builtin_amdgcn_mfma_f32_16x16x32_bf16(kf0, qf0, sacc[jb], 0, 0, 0);
      sacc[jb] = __builtin_amdgcn_mfma_f32_16x16x32_bf16(kf1, qf1, sacc[jb], 0, 0, 0);
    }
    float s2[16];
    float rmax = -1e30f;
    #pragma unroll
    for (int jb = 0; jb < 4; ++jb) {
      float4 z4 = *(const float4*)(zrow + j0 + jb * 16 + g * 4);
      s2[jb*4+0] = fmaf(sacc[jb][0], QKS, z4.x);
      s2[jb*4+1] = fmaf(sacc[jb][1], QKS, z4.y);
      s2[jb*4+2] = fmaf(sacc[jb][2], QKS, z4.z);
      s2[jb*4+3] = fmaf(sacc[jb][3], QKS, z4.w);
      rmax = fmaxf(rmax, fmaxf(fmaxf(s2[jb*4+0], s2[jb*4+1]), fmaxf(s2[jb*4+2], s2[jb*4+3])));
    }
    rmax = fmaxf(rmax, __shfl_xor(rmax, 16));
    rmax = fmaxf(rmax, __shfl_xor(rmax, 32));
    float mnew = fmaxf(mrun, rmax);
    float scale = exp2f(mrun - mnew);
    float rsum = 0.f;
    unsigned int c0[4], c1[4];
    #pragma unroll
    for (int jb = 0; jb < 4; ++jb) {
      float p0 = exp2f(s2[jb*4+0] - mnew);
      float p1 = exp2f(s2[jb*4+1] - mnew);
      float p2 = exp2f(s2[jb*4+2] - mnew);
      float p3 = exp2f(s2[jb*4+3] - mnew);
      rsum += (p0 + p1) + (p2 + p3);
      c0[jb] = cvtpk_bf16(p0, p1);
      c1[jb] = cvtpk_bf16(p2, p3);
    }
    rsum += __shfl_xor(rsum, 16);
    rsum += __shfl_xor(rsum, 32);
    lrun = fmaf(lrun, scale, rsum);
    mrun = mnew;
    #pragma unroll
    for (int db = 0; db < 4; ++db) {
      oacc[db][0] *= scale; oacc[db][1] *= scale;
      oacc[db][2] *= scale; oacc[db][3] *= scale;
    }
    #pragma unroll
    for (int js = 0; js < 2; ++js) {
      int srcLo = ((g & 1) << 5) + il;
      int srcHi = srcLo + 16;
      unsigned int a0 = (unsigned int)__shfl((int)c0[2*js],     srcLo);
      unsigned int b0 = (unsigned int)__shfl((int)c0[2*js + 1], srcLo);
      unsigned int a1 = (unsigned int)__shfl((int)c1[2*js],     srcLo);
      unsigned int b1 = (unsigned int)__shfl((int)c1[2*js + 1], srcLo);
      unsigned int a2 = (unsigned int)__shfl((int)c0[2*js],     srcHi);
      unsigned int b2 = (unsigned int)__shfl((int)c0[2*js + 1], srcHi);
      unsigned int a3 = (unsigned int)__shfl((int)c1[2*js],     srcHi);
      unsigned int b3 = (unsigned int)__shfl((int)c1[2*js + 1], srcHi);
      bool hi = (g & 2) != 0;
      union { unsigned int u[4]; bf16x8 v; } pb;
      pb.u[0] = hi ? b0 : a0;
      pb.u[1] = hi ? b1 : a1;
      pb.u[2] = hi ? b2 : a2;
      pb.u[3] = hi ? b3 : a3;
      #pragma unroll
      for (int db = 0; db < 4; ++db) {
        bf16x8 vf = *(const bf16x8*)(vtb + (size_t)(h * HD + db * 16 + il) * NTOK + j0 + js * 32 + g * 8);
        oacc[db] = __builtin_amdgcn_mfma_f32_16x16x32_bf16(vf, pb.v, oacc[db], 0, 0, 0);
      }
    }
  }
  float* obase = Opart + ((size_t)(jc * NH + h) << 16) + ((size_t)irow << 6);
  #pragma unroll
  for (int db = 0; db < 4; ++db)
    *(float4*)(obase + db * 16 + g * 4) = *(float4*)&oacc[db];
  if (g == 0)
    ml[((jc * NH + h) << 10) + irow] = make_float2(mrun, lrun);
}

// ---------------- combine partials + gating -> gob (bf16) ----------------
__global__ __launch_bounds__(256) void combine_kernel(const float* __restrict__ Opart,
    const float2* __restrict__ ml, const unsigned short* __restrict__ gbuf,
    unsigned short* __restrict__ gob) {
  int t = threadIdx.x;
  int r = blockIdx.x * 4 + (t >> 6);       // (h,i) row index
  int h = r >> 10, i = r & (NTOK - 1), d = t & 63;
  float2 mlv[JC];
  float m = -1e30f;
  #pragma unroll
  for (int c = 0; c < JC; ++c) {
    mlv[c] = ml[((c * NH + h) << 10) + i];
    m = fmaxf(m, mlv[c].x);
  }
  float w[JC], ltot = 0.f;
  #pragma unroll
  for (int c = 0; c < JC; ++c) {
    w[c] = exp2f(mlv[c].x - m);
    ltot = fmaf(mlv[c].y, w[c], ltot);
  }
  float inv = 1.f / ltot;
  float o = 0.f;
  #pragma unroll
  for (int c = 0; c < JC; ++c)
    o = fmaf(Opart[((size_t)(c * NH + h) << 16) + ((size_t)i << 6) + d], w[c], o);
  size_t off = (size_t)i * CS + h * HD + d;
  gob[off] = f2bf(o * inv * bf2f(gbuf[off]));
}

// ---------------- final GEMM: out = gob @ Wo  (f32 out) ----------------
__global__ __launch_bounds__(256) void out_gemm(const unsigned short* __restrict__ A,
    const unsigned short* __restrict__ Bt, float* __restrict__ C) {
  __shared__ __align__(16) unsigned short As[64][40];
  __shared__ __align__(16) unsigned short Bs[64][40];
  int tid = threadIdx.x;
  int wid = tid >> 6, lane = tid & 63;
  int lrow = lane & 15, lk8 = (lane >> 4) * 8;
  int row0 = blockIdx.y * 64, col0 = blockIdx.x * 64;
  int ar = tid >> 2, ak = (tid & 3) * 8;
  f32x4 acc[4] = {};
  for (int k0 = 0; k0 < CS; k0 += 32) {
    *(ushort8_t*)&As[ar][ak] = *(const ushort8_t*)(A  + (size_t)(row0 + ar) * CS + k0 + ak);
    *(ushort8_t*)&Bs[ar][ak] = *(const ushort8_t*)(Bt + (size_t)(col0 + ar) * CS + k0 + ak);
    __syncthreads();
    bf16x8 af = *(bf16x8*)&As[wid * 16 + lrow][lk8];
    #pragma unroll
    for (int nb = 0; nb < 4; ++nb) {
      bf16x8 bfr = *(bf16x8*)&Bs[nb * 16 + lrow][lk8];
      acc[nb] = __builtin_amdgcn_mfma_f32_16x16x32_bf16(af, bfr, acc[nb], 0, 0, 0);
    }
    __syncthreads();
  }
  #pragma unroll
  for (int nb = 0; nb < 4; ++nb) {
    int gcol = col0 + nb * 16 + lrow;
    #pragma unroll
    for (int r = 0; r < 4; ++r) {
      int grow = row0 + wid * 16 + (lane >> 4) * 4 + r;
      C[(size_t)grow * CS + gcol] = acc[nb][r];
    }
  }
}

extern "C" void kernel_launch(void* const* d_in, const int* in_sizes, int n_in,
                              void* d_out, int out_size, void* d_ws, size_t ws_size,
                              hipStream_t stream) {
  const float* s    = (const float*)d_in[0];
  const float* z    = (const float*)d_in[1];
  const float* mask = (const float*)d_in[2];
  const float* nss  = (const float*)d_in[3];
  const float* nsb  = (const float*)d_in[4];
  const float* Wq   = (const float*)d_in[5];
  const float* bq   = (const float*)d_in[6];
  const float* Wk   = (const float*)d_in[7];
  const float* Wv   = (const float*)d_in[8];
  const float* Wg   = (const float*)d_in[9];
  const float* nzs  = (const float*)d_in[10];
  const float* nzb  = (const float*)d_in[11];
  const float* Wz   = (const float*)d_in[12];
  const float* Wo   = (const float*)d_in[13];
  float* out = (float*)d_out;

  const size_t SN = (size_t)NTOK * CS;        // 786432
  const size_t NPAIR = (size_t)NTOK * NTOK;   // 1M
  const size_t WSZ = (size_t)CS * CS;         // 589824

  float* zbuf  = (float*)d_ws;                         // 12M f32
  float* Opart = zbuf + NH * NPAIR;                    // JC*12*1024*64 f32 = 3M f32
  float2* ml   = (float2*)(Opart + (size_t)JC * NH * NTOK * HD);  // JC*12*1024 float2
  unsigned short* sn  = (unsigned short*)(ml + (size_t)JC * NH * NTOK);
  unsigned short* qb  = sn  + SN;
  unsigned short* kb  = qb  + SN;
  unsigned short* vtb = kb  + SN;                      // [768][1024] transposed V
  unsigned short* gbuf= vtb + SN;
  unsigned short* gob = gbuf+ SN;
  unsigned short* wt  = gob + SN;                      // 5 x [768][768]

  prep_kernel<<<NTOK + 720, 256, 0, stream>>>(s, nss, nsb, sn, Wq, Wk, Wv, Wg, Wo, wt);
  zbqkvg_kernel<<<NZB + 768, 256, 0, stream>>>(z, nzs, nzb, Wz, mask, zbuf,
                                               sn, wt, bq, qb, kb, vtb, gbuf);
  flash_part<<<dim3(NH, 16, JC), 256, 0, stream>>>(qb, kb, vtb, zbuf, Opart, ml);
  combine_kernel<<<NH * NTOK / 4, 256, 0, stream>>>(Opart, ml, gbuf, gob);
  out_gemm<<<dim3(12, 16), 256, 0, stream>>>(gob, wt + 4 * WSZ, out);
}

// Round 6
// 202.158 us; speedup vs baseline: 6.1189x; 1.0065x over previous
//
#include <hip/hip_runtime.h>
#include <hip/hip_bf16.h>

#define CS 768
#define NTOK 1024
#define CZ 128
#define NH 12
#define HD 64
#define NZB 2048          // zb blocks in the heterogeneous kernel
#define JC 8              // flash j-split chunks

typedef __attribute__((ext_vector_type(8))) short bf16x8;
typedef __attribute__((ext_vector_type(4))) float f32x4;
typedef __attribute__((ext_vector_type(8))) unsigned short ushort8_t;
typedef __attribute__((ext_vector_type(4))) unsigned short ushort4_t;

__device__ inline unsigned short f2bf(float f) {
  __hip_bfloat16 h = __float2bfloat16(f);
  return *reinterpret_cast<unsigned short*>(&h);
}
__device__ inline float bf2f(unsigned short u) {
  union { unsigned int i; float f; } c; c.i = ((unsigned int)u) << 16;
  return c.f;
}
__device__ inline unsigned int cvtpk_bf16(float lo, float hi) {
  unsigned int r;
  asm("v_cvt_pk_bf16_f32 %0, %1, %2" : "=v"(r) : "v"(lo), "v"(hi));
  return r;
}

// ---------------- prep: LN(s)->bf16  +  transpose/convert 5 weights ----------------
__global__ __launch_bounds__(256) void prep_kernel(const float* __restrict__ s,
    const float* __restrict__ sc, const float* __restrict__ bi, unsigned short* __restrict__ sn,
    const float* __restrict__ W0, const float* __restrict__ W1, const float* __restrict__ W2,
    const float* __restrict__ W3, const float* __restrict__ W4, unsigned short* __restrict__ wt) {
  __shared__ float tile[64][65];
  int tid = threadIdx.x;
  if (blockIdx.x < NTOK) {
    int row = blockIdx.x;
    const float* x = s + (size_t)row * CS;
    float v0 = x[tid], v1 = x[tid + 256], v2 = x[tid + 512];
    float sum = v0 + v1 + v2;
    float sq  = v0*v0 + v1*v1 + v2*v2;
    for (int off = 1; off < 64; off <<= 1) {
      sum += __shfl_xor(sum, off);
      sq  += __shfl_xor(sq,  off);
    }
    __shared__ float ws1[4], ws2[4];
    if ((tid & 63) == 0) { ws1[tid >> 6] = sum; ws2[tid >> 6] = sq; }
    __syncthreads();
    float S = ws1[0] + ws1[1] + ws1[2] + ws1[3];
    float Q = ws2[0] + ws2[1] + ws2[2] + ws2[3];
    float mu  = S * (1.f / CS);
    float var = Q * (1.f / CS) - mu * mu;
    float rs  = rsqrtf(var + 1e-5f);
    unsigned short* y = sn + (size_t)row * CS;
    y[tid]       = f2bf((v0 - mu) * rs * sc[tid]       + bi[tid]);
    y[tid + 256] = f2bf((v1 - mu) * rs * sc[tid + 256] + bi[tid + 256]);
    y[tid + 512] = f2bf((v2 - mu) * rs * sc[tid + 512] + bi[tid + 512]);
  } else {
    int bz = blockIdx.x - NTOK;           // [0, 720)
    int w = bz / 144, rem = bz % 144;
    int kt = rem % 12, nt = rem / 12;
    const float* W = w == 0 ? W0 : w == 1 ? W1 : w == 2 ? W2 : w == 3 ? W3 : W4;
    unsigned short* Wt = wt + (size_t)w * CS * CS;
    int k0 = kt * 64, n0 = nt * 64;
    #pragma unroll
    for (int it = 0; it < 4; ++it) {
      int r = (tid >> 4) + it * 16;
      int c = (tid & 15) * 4;
      float4 vv = *(const float4*)(W + (size_t)(k0 + r) * CS + n0 + c);
      tile[r][c] = vv.x; tile[r][c+1] = vv.y; tile[r][c+2] = vv.z; tile[r][c+3] = vv.w;
    }
    __syncthreads();
    #pragma unroll
    for (int it = 0; it < 2; ++it) {
      int idx = tid + it * 256;
      int n = idx >> 3, k8 = (idx & 7) * 8;
      ushort8_t o;
      #pragma unroll
      for (int e = 0; e < 8; ++e) o[e] = f2bf(tile[k8 + e][n]);
      *(ushort8_t*)(Wt + (size_t)(n0 + n) * CS + k0 + k8) = o;
    }
  }
}

// ---------------- heterogeneous: zb (MFMA, blocks 0..NZB) + qkvg GEMM (blocks NZB..) ----------------
// zb math: (LN_raw(z)*sc + bi) @ Wz  ==  LN_raw(z) @ (sc*Wz)  +  (bi @ Wz)   [exact]
__global__ __launch_bounds__(256) void zbqkvg_kernel(const float* __restrict__ z,
    const float* __restrict__ gs, const float* __restrict__ gb,
    const float* __restrict__ Wz, const float* __restrict__ mask, float* __restrict__ zbuf,
    const unsigned short* __restrict__ A, const unsigned short* __restrict__ Wt,
    const float* __restrict__ bq, unsigned short* __restrict__ qb,
    unsigned short* __restrict__ kb, unsigned short* __restrict__ vtb,
    unsigned short* __restrict__ gbuf) {
  __shared__ __align__(16) unsigned short As[64][40];
  __shared__ __align__(16) unsigned short Bs[64][40];
  int tid = threadIdx.x;
  if (blockIdx.x < NZB) {
    // ---- zb path ----
    const int lane = tid & 63;
    const int il = lane & 15;
    const int qg = lane >> 4;
    const size_t NPAIR = (size_t)NTOK * NTOK;
    // Build split-bf16 fragments of W' = sc*Wz for this lane's 32 channels; partial bias-dot.
    bf16x8 whi[4], wlo[4];
    float bh = 0.f;
    #pragma unroll
    for (int m = 0; m < 4; ++m) {
      union { unsigned short u[8]; bf16x8 v; } hi, lo;
      #pragma unroll
      for (int e = 0; e < 8; ++e) {
        int c = 32 * m + 8 * qg + e;
        float wv = (il < NH) ? Wz[c * NH + il] : 0.f;
        bh = fmaf(gb[c], wv, bh);
        float wp = gs[c] * wv;
        unsigned short h = f2bf(wp);
        hi.u[e] = h;
        lo.u[e] = f2bf(wp - bf2f(h));
      }
      whi[m] = hi.v; wlo[m] = lo.v;
    }
    bh += __shfl_xor(bh, 16);
    bh += __shfl_xor(bh, 32);

    const int wave = blockIdx.x * 4 + (tid >> 6);
    const int nWaves = NZB * 4;
    for (size_t p0 = (size_t)wave * 16; p0 < NPAIR; p0 += (size_t)nWaves * 16) {
      const float* zrow = z + (p0 + il) * CZ;
      float zv[32];
      #pragma unroll
      for (int m = 0; m < 4; ++m) {
        float4 a = *(const float4*)(zrow + 32 * m + 8 * qg);
        float4 b = *(const float4*)(zrow + 32 * m + 8 * qg + 4);
        zv[m*8+0] = a.x; zv[m*8+1] = a.y; zv[m*8+2] = a.z; zv[m*8+3] = a.w;
        zv[m*8+4] = b.x; zv[m*8+5] = b.y; zv[m*8+6] = b.z; zv[m*8+7] = b.w;
      }
      float sum = 0.f, sq = 0.f;
      #pragma unroll
      for (int e = 0; e < 32; ++e) { sum += zv[e]; sq = fmaf(zv[e], zv[e], sq); }
      sum += __shfl_xor(sum, 16); sum += __shfl_xor(sum, 32);
      sq  += __shfl_xor(sq,  16); sq  += __shfl_xor(sq,  32);
      float mu  = sum * (1.f / CZ);
      float var = sq * (1.f / CZ) - mu * mu;
      float rs  = rsqrtf(var + 1e-5f);
      float nmr = -mu * rs;
      bf16x8 ahi[4], alo[4];
      #pragma unroll
      for (int m = 0; m < 4; ++m) {
        union { unsigned short u[8]; bf16x8 v; } hi, lo;
        #pragma unroll
        for (int e = 0; e < 8; ++e) {
          float nv = fmaf(zv[m*8+e], rs, nmr);
          unsigned short h = f2bf(nv);
          hi.u[e] = h;
          lo.u[e] = f2bf(nv - bf2f(h));
        }
        ahi[m] = hi.v; alo[m] = lo.v;
      }
      f32x4 acc = {};
      #pragma unroll
      for (int m = 0; m < 4; ++m) {
        acc = __builtin_amdgcn_mfma_f32_16x16x32_bf16(ahi[m], whi[m], acc, 0, 0, 0);
        acc = __builtin_amdgcn_mfma_f32_16x16x32_bf16(alo[m], whi[m], acc, 0, 0, 0);
        acc = __builtin_amdgcn_mfma_f32_16x16x32_bf16(ahi[m], wlo[m], acc, 0, 0, 0);
      }
      if (il < NH) {
        int j0 = (int)(p0 & (NTOK - 1)) + 4 * qg;
        float4 mk = *(const float4*)(mask + j0);
        float4 o;
        o.x = (acc[0] + bh + (1.f - mk.x) * -1000000.0f) * 1.44269504f;
        o.y = (acc[1] + bh + (1.f - mk.y) * -1000000.0f) * 1.44269504f;
        o.z = (acc[2] + bh + (1.f - mk.z) * -1000000.0f) * 1.44269504f;
        o.w = (acc[3] + bh + (1.f - mk.w) * -1000000.0f) * 1.44269504f;
        *(float4*)(zbuf + (size_t)il * NPAIR + p0 + 4 * qg) = o;
      }
    }
  } else {
    // ---- qkvg path ----
    int bx = blockIdx.x - NZB;           // [0, 768)
    int wid = tid >> 6, lane = tid & 63;
    int lrow = lane & 15, lk8 = (lane >> 4) * 8;
    int row0 = (bx / 48) * 64, col0 = (bx % 48) * 64;   // col0 in [0,3072)
    int ar = tid >> 2, ak = (tid & 3) * 8;
    f32x4 acc[4] = {};
    for (int k0 = 0; k0 < CS; k0 += 32) {
      *(ushort8_t*)&As[ar][ak] = *(const ushort8_t*)(A  + (size_t)(row0 + ar) * CS + k0 + ak);
      *(ushort8_t*)&Bs[ar][ak] = *(const ushort8_t*)(Wt + (size_t)(col0 + ar) * CS + k0 + ak);
      __syncthreads();
      bf16x8 af = *(bf16x8*)&As[wid * 16 + lrow][lk8];
      #pragma unroll
      for (int nb = 0; nb < 4; ++nb) {
        bf16x8 bfr = *(bf16x8*)&Bs[nb * 16 + lrow][lk8];
        acc[nb] = __builtin_amdgcn_mfma_f32_16x16x32_bf16(af, bfr, acc[nb], 0, 0, 0);
      }
      __syncthreads();
    }
    int sect = col0 / CS;          // 0=q 1=k 2=v 3=g
    int ncol0 = col0 - sect * CS;
    int grow0 = row0 + wid * 16 + (lane >> 4) * 4;
    if (sect == 2) {
      #pragma unroll
      for (int nb = 0; nb < 4; ++nb) {
        int dg = ncol0 + nb * 16 + lrow;
        ushort4_t o;
        #pragma unroll
        for (int r = 0; r < 4; ++r) o[r] = f2bf(acc[nb][r]);
        *(ushort4_t*)(vtb + (size_t)dg * NTOK + grow0) = o;
      }
    } else {
      unsigned short* dst = sect == 0 ? qb : sect == 1 ? kb : gbuf;
      #pragma unroll
      for (int nb = 0; nb < 4; ++nb) {
        int gcol = ncol0 + nb * 16 + lrow;
        float bv = (sect == 0) ? bq[gcol] : 0.f;
        #pragma unroll
        for (int r = 0; r < 4; ++r) {
          float val = acc[nb][r] + bv;
          if (sect == 3) val = 1.f / (1.f + __expf(-val));
          dst[(size_t)(grow0 + r) * CS + gcol] = f2bf(val);
        }
      }
    }
  }
}

// ---------------- flash partial: j-chunk flash attention, writes O-partial + (m,l) ----------------
__global__ __launch_bounds__(256) void flash_part(
    const unsigned short* __restrict__ qb, const unsigned short* __restrict__ kb,
    const unsigned short* __restrict__ vtb, const float* __restrict__ zbuf,
    float* __restrict__ Opart, float2* __restrict__ ml) {
  const int h = blockIdx.x;
  const int i0 = blockIdx.y * 64;
  const int jc = blockIdx.z;
  const int w = threadIdx.x >> 6, lane = threadIdx.x & 63;
  const int il = lane & 15, g = lane >> 4;
  const int irow = i0 + w * 16 + il;
  const float QKS = 0.125f * 1.44269504f;

  bf16x8 qf0 = *(const bf16x8*)(qb + (size_t)irow * CS + h * HD + g * 8);
  bf16x8 qf1 = *(const bf16x8*)(qb + (size_t)irow * CS + h * HD + 32 + g * 8);

  f32x4 oacc[4] = {};
  float mrun = -1e30f, lrun = 0.f;
  const float* zrow = zbuf + ((size_t)h << 20) + ((size_t)irow << 10);

  const int jlo = jc * (NTOK / JC), jhi = jlo + (NTOK / JC);
  for (int j0 = jlo; j0 < jhi; j0 += 64) {
    f32x4 sacc[4] = {};
    #pragma unroll
    for (int jb = 0; jb < 4; ++jb) {
      const unsigned short* kbase = kb + (size_t)(j0 + jb * 16 + il) * CS + h * HD;
      bf16x8 kf0 = *(const bf16x8*)(kbase + g * 8);
      bf16x8 kf1 = *(const bf16x8*)(kbase + 32 + g * 8);
      sacc[jb] = __builtin_amdgcn_mfma_f32_16x16x32_bf16(kf0, qf0, sacc[jb], 0, 0, 0);
      sacc[jb] = __builtin_amdgcn_mfma_f32_16x16x32_bf16(kf1, qf1, sacc[jb], 0, 0, 0);
    }
    float s2[16];
    float rmax = -1e30f;
    #pragma unroll
    for (int jb = 0; jb < 4; ++jb) {
      float4 z4 = *(const float4*)(zrow + j0 + jb * 16 + g * 4);
      s2[jb*4+0] = fmaf(sacc[jb][0], QKS, z4.x);
      s2[jb*4+1] = fmaf(sacc[jb][1], QKS, z4.y);
      s2[jb*4+2] = fmaf(sacc[jb][2], QKS, z4.z);
      s2[jb*4+3] = fmaf(sacc[jb][3], QKS, z4.w);
      rmax = fmaxf(rmax, fmaxf(fmaxf(s2[jb*4+0], s2[jb*4+1]), fmaxf(s2[jb*4+2], s2[jb*4+3])));
    }
    rmax = fmaxf(rmax, __shfl_xor(rmax, 16));
    rmax = fmaxf(rmax, __shfl_xor(rmax, 32));
    float mnew = fmaxf(mrun, rmax);
    float scale = exp2f(mrun - mnew);
    float rsum = 0.f;
    unsigned int c0[4], c1[4];
    #pragma unroll
    for (int jb = 0; jb < 4; ++jb) {
      float p0 = exp2f(s2[jb*4+0] - mnew);
      float p1 = exp2f(s2[jb*4+1] - mnew);
      float p2 = exp2f(s2[jb*4+2] - mnew);
      float p3 = exp2f(s2[jb*4+3] - mnew);
      rsum += (p0 + p1) + (p2 + p3);
      c0[jb] = cvtpk_bf16(p0, p1);
      c1[jb] = cvtpk_bf16(p2, p3);
    }
    rsum += __shfl_xor(rsum, 16);
    rsum += __shfl_xor(rsum, 32);
    lrun = fmaf(lrun, scale, rsum);
    mrun = mnew;
    #pragma unroll
    for (int db = 0; db < 4; ++db) {
      oacc[db][0] *= scale; oacc[db][1] *= scale;
      oacc[db][2] *= scale; oacc[db][3] *= scale;
    }
    #pragma unroll
    for (int js = 0; js < 2; ++js) {
      int srcLo = ((g & 1) << 5) + il;
      int srcHi = srcLo + 16;
      unsigned int a0 = (unsigned int)__shfl((int)c0[2*js],     srcLo);
      unsigned int b0 = (unsigned int)__shfl((int)c0[2*js + 1], srcLo);
      unsigned int a1 = (unsigned int)__shfl((int)c1[2*js],     srcLo);
      unsigned int b1 = (unsigned int)__shfl((int)c1[2*js + 1], srcLo);
      unsigned int a2 = (unsigned int)__shfl((int)c0[2*js],     srcHi);
      unsigned int b2 = (unsigned int)__shfl((int)c0[2*js + 1], srcHi);
      unsigned int a3 = (unsigned int)__shfl((int)c1[2*js],     srcHi);
      unsigned int b3 = (unsigned int)__shfl((int)c1[2*js + 1], srcHi);
      bool hi = (g & 2) != 0;
      union { unsigned int u[4]; bf16x8 v; } pb;
      pb.u[0] = hi ? b0 : a0;
      pb.u[1] = hi ? b1 : a1;
      pb.u[2] = hi ? b2 : a2;
      pb.u[3] = hi ? b3 : a3;
      #pragma unroll
      for (int db = 0; db < 4; ++db) {
        bf16x8 vf = *(const bf16x8*)(vtb + (size_t)(h * HD + db * 16 + il) * NTOK + j0 + js * 32 + g * 8);
        oacc[db] = __builtin_amdgcn_mfma_f32_16x16x32_bf16(vf, pb.v, oacc[db], 0, 0, 0);
      }
    }
  }
  float* obase = Opart + ((size_t)(jc * NH + h) << 16) + ((size_t)irow << 6);
  #pragma unroll
  for (int db = 0; db < 4; ++db)
    *(float4*)(obase + db * 16 + g * 4) = *(float4*)&oacc[db];
  if (g == 0)
    ml[((jc * NH + h) << 10) + irow] = make_float2(mrun, lrun);
}

// ---------------- combine partials + gating -> gob (bf16) ----------------
__global__ __launch_bounds__(256) void combine_kernel(const float* __restrict__ Opart,
    const float2* __restrict__ ml, const unsigned short* __restrict__ gbuf,
    unsigned short* __restrict__ gob) {
  int t = threadIdx.x;
  int r = blockIdx.x * 4 + (t >> 6);       // (h,i) row index
  int h = r >> 10, i = r & (NTOK - 1), d = t & 63;
  float2 mlv[JC];
  float m = -1e30f;
  #pragma unroll
  for (int c = 0; c < JC; ++c) {
    mlv[c] = ml[((c * NH + h) << 10) + i];
    m = fmaxf(m, mlv[c].x);
  }
  float w[JC], ltot = 0.f;
  #pragma unroll
  for (int c = 0; c < JC; ++c) {
    w[c] = exp2f(mlv[c].x - m);
    ltot = fmaf(mlv[c].y, w[c], ltot);
  }
  float inv = 1.f / ltot;
  float o = 0.f;
  #pragma unroll
  for (int c = 0; c < JC; ++c)
    o = fmaf(Opart[((size_t)(c * NH + h) << 16) + ((size_t)i << 6) + d], w[c], o);
  size_t off = (size_t)i * CS + h * HD + d;
  gob[off] = f2bf(o * inv * bf2f(gbuf[off]));
}

// ---------------- final GEMM: out = gob @ Wo  (f32 out) ----------------
__global__ __launch_bounds__(256) void out_gemm(const unsigned short* __restrict__ A,
    const unsigned short* __restrict__ Bt, float* __restrict__ C) {
  __shared__ __align__(16) unsigned short As[64][40];
  __shared__ __align__(16) unsigned short Bs[64][40];
  int tid = threadIdx.x;
  int wid = tid >> 6, lane = tid & 63;
  int lrow = lane & 15, lk8 = (lane >> 4) * 8;
  int row0 = blockIdx.y * 64, col0 = blockIdx.x * 64;
  int ar = tid >> 2, ak = (tid & 3) * 8;
  f32x4 acc[4] = {};
  for (int k0 = 0; k0 < CS; k0 += 32) {
    *(ushort8_t*)&As[ar][ak] = *(const ushort8_t*)(A  + (size_t)(row0 + ar) * CS + k0 + ak);
    *(ushort8_t*)&Bs[ar][ak] = *(const ushort8_t*)(Bt + (size_t)(col0 + ar) * CS + k0 + ak);
    __syncthreads();
    bf16x8 af = *(bf16x8*)&As[wid * 16 + lrow][lk8];
    #pragma unroll
    for (int nb = 0; nb < 4; ++nb) {
      bf16x8 bfr = *(bf16x8*)&Bs[nb * 16 + lrow][lk8];
      acc[nb] = __builtin_amdgcn_mfma_f32_16x16x32_bf16(af, bfr, acc[nb], 0, 0, 0);
    }
    __syncthreads();
  }
  #pragma unroll
  for (int nb = 0; nb < 4; ++nb) {
    int gcol = col0 + nb * 16 + lrow;
    #pragma unroll
    for (int r = 0; r < 4; ++r) {
      int grow = row0 + wid * 16 + (lane >> 4) * 4 + r;
      C[(size_t)grow * CS + gcol] = acc[nb][r];
    }
  }
}

extern "C" void kernel_launch(void* const* d_in, const int* in_sizes, int n_in,
                              void* d_out, int out_size, void* d_ws, size_t ws_size,
                              hipStream_t stream) {
  const float* s    = (const float*)d_in[0];
  const float* z    = (const float*)d_in[1];
  const float* mask = (const float*)d_in[2];
  const float* nss  = (const float*)d_in[3];
  const float* nsb  = (const float*)d_in[4];
  const float* Wq   = (const float*)d_in[5];
  const float* bq   = (const float*)d_in[6];
  const float* Wk   = (const float*)d_in[7];
  const float* Wv   = (const float*)d_in[8];
  const float* Wg   = (const float*)d_in[9];
  const float* nzs  = (const float*)d_in[10];
  const float* nzb  = (const float*)d_in[11];
  const float* Wz   = (const float*)d_in[12];
  const float* Wo   = (const float*)d_in[13];
  float* out = (float*)d_out;

  const size_t SN = (size_t)NTOK * CS;        // 786432
  const size_t NPAIR = (size_t)NTOK * NTOK;   // 1M
  const size_t WSZ = (size_t)CS * CS;         // 589824

  float* zbuf  = (float*)d_ws;                         // 12M f32
  float* Opart = zbuf + NH * NPAIR;                    // JC*12*1024*64 f32
  float2* ml   = (float2*)(Opart + (size_t)JC * NH * NTOK * HD);  // JC*12*1024 float2
  unsigned short* sn  = (unsigned short*)(ml + (size_t)JC * NH * NTOK);
  unsigned short* qb  = sn  + SN;
  unsigned short* kb  = qb  + SN;
  unsigned short* vtb = kb  + SN;                      // [768][1024] transposed V
  unsigned short* gbuf= vtb + SN;
  unsigned short* gob = gbuf+ SN;
  unsigned short* wt  = gob + SN;                      // 5 x [768][768]

  prep_kernel<<<NTOK + 720, 256, 0, stream>>>(s, nss, nsb, sn, Wq, Wk, Wv, Wg, Wo, wt);
  zbqkvg_kernel<<<NZB + 768, 256, 0, stream>>>(z, nzs, nzb, Wz, mask, zbuf,
                                               sn, wt, bq, qb, kb, vtb, gbuf);
  flash_part<<<dim3(NH, 16, JC), 256, 0, stream>>>(qb, kb, vtb, zbuf, Opart, ml);
  combine_kernel<<<NH * NTOK / 4, 256, 0, stream>>>(Opart, ml, gbuf, gob);
  out_gemm<<<dim3(12, 16), 256, 0, stream>>>(gob, wt + 4 * WSZ, out);
}